// Round 5
// baseline (872.303 us; speedup 1.0000x reference)
//
#include <hip/hip_runtime.h>
#include <math.h>

// EGAT GNN forward — round 5: scores fused into the e@we GEMM epilogue (ewb
// buffer deleted), xfull stored lane-permuted for 16B epilogue gathers,
// node_fused reduced to softmax+aggregate only, scatter+permute fused.
#define NN 50000      // N_NODES
#define NE 320000     // N_EDGES
#define BATCH 4096

typedef __bf16 bf16x8 __attribute__((ext_vector_type(8)));
typedef float floatx4 __attribute__((ext_vector_type(4)));
typedef unsigned short ushort;
typedef unsigned int uint;

__device__ __forceinline__ float lrelu02(float x) { return x > 0.f ? x : 0.2f * x; }
__device__ __forceinline__ float b2f(ushort h) { return __uint_as_float(((uint)h) << 16); }
__device__ __forceinline__ float b2f_lo(uint u) { return __uint_as_float(u << 16); }
__device__ __forceinline__ float b2f_hi(uint u) { return __uint_as_float(u & 0xffff0000u); }
__device__ __forceinline__ ushort f2b(float x) {
    uint u = __float_as_uint(x);
    return (ushort)((u + 0x7fffu + ((u >> 16) & 1u)) >> 16);  // RNE
}
__device__ __forceinline__ void unpack8(uint4 v, float* f) {
    f[0] = b2f_lo(v.x); f[1] = b2f_hi(v.x); f[2] = b2f_lo(v.y); f[3] = b2f_hi(v.y);
    f[4] = b2f_lo(v.z); f[5] = b2f_hi(v.z); f[6] = b2f_lo(v.w); f[7] = b2f_hi(v.w);
}

// ---------------------------------------------------------------------------
// bf16 MFMA GEMM, C tile 64 x 16*NT per block (4 waves). A (M x K, lda) bf16
// or fp32 (AF32: convert during staging; cols >= Kreal read 0).
// Bt = B^T ((16*NT) x K bf16). Epilogues:
//  EPI 1 (NT=4): +bias, act (0=ELU, 1=lrelu0.01), bf16 write row-major ld 64.
//  EPI 2 (NT=16): lane-permuted xfull write — col 16c+l16 stored at
//                 half*128 + l16*8 + (c&7), halves c<8 (xi) / c>=8 (xj).
//  EPI 3 (NT=8): score epilogue — gather xi[src],xj[dst] (permuted layout),
//                f=lrelu(ew+xi+xj), ph=sum f*attn per head, 16-lane reduce,
//                scatter float4 score to scv[posv[row]*4].
// ---------------------------------------------------------------------------
template <int NT, int EPI, int AF32>
__global__ __launch_bounds__(256) void gemm_bf16(
    const void* __restrict__ Av, int lda, int M, int K, int Kreal,
    const ushort* __restrict__ Bt,
    ushort* __restrict__ outb,
    const float* __restrict__ bias, int act,
    const int* __restrict__ srcv, const int* __restrict__ dstv,
    const int* __restrict__ posv,
    const ushort* __restrict__ xfull, const float* __restrict__ attn,
    float* __restrict__ scv)
{
    constexpr int NC = 16 * NT;
    __shared__ __align__(16) ushort As[64 * 32];
    __shared__ __align__(16) ushort Bs[NC * 32];
    const int tid = threadIdx.x;
    const int row0 = blockIdx.x << 6;
    const int w = tid >> 6, lane = tid & 63;
    const int quad = lane >> 4, l16 = lane & 15;
    const int arow = tid >> 2, akc = (tid & 3) << 3;

    floatx4 acc[NT];
#pragma unroll
    for (int c = 0; c < NT; c++)
#pragma unroll
        for (int r = 0; r < 4; r++) acc[c][r] = 0.f;

    for (int kt = 0; kt < K; kt += 32) {
        uint4 av = make_uint4(0u, 0u, 0u, 0u);
        if (AF32) {
            if (row0 + arow < M && kt + akc < Kreal) {
                const float* ap = (const float*)Av + (size_t)(row0 + arow) * lda + kt + akc;
                float4 f0 = *(const float4*)ap;
                float4 f1 = *(const float4*)(ap + 4);
                av.x = (uint)f2b(f0.x) | ((uint)f2b(f0.y) << 16);
                av.y = (uint)f2b(f0.z) | ((uint)f2b(f0.w) << 16);
                av.z = (uint)f2b(f1.x) | ((uint)f2b(f1.y) << 16);
                av.w = (uint)f2b(f1.z) | ((uint)f2b(f1.w) << 16);
            }
        } else {
            if (row0 + arow < M)
                av = *(const uint4*)((const ushort*)Av + (size_t)(row0 + arow) * lda + kt + akc);
        }
        *(uint4*)(As + arow * 32 + akc) = av;
#pragma unroll
        for (int it = 0; it < NT / 4; it++) {
            int idx = it * 256 + tid;
            int bn = idx >> 2, bkc = (idx & 3) << 3;
            *(uint4*)(Bs + bn * 32 + bkc) =
                *(const uint4*)(Bt + (size_t)bn * K + kt + bkc);
        }
        __syncthreads();
        bf16x8 af = *(const bf16x8*)(As + (16 * w + l16) * 32 + quad * 8);
#pragma unroll
        for (int c = 0; c < NT; c++) {
            bf16x8 bfv = *(const bf16x8*)(Bs + (16 * c + l16) * 32 + quad * 8);
            acc[c] = __builtin_amdgcn_mfma_f32_16x16x32_bf16(af, bfv, acc[c], 0, 0, 0);
        }
        __syncthreads();
    }

    if (EPI == 1) {
#pragma unroll
        for (int r = 0; r < 4; r++) {
            int gr = row0 + 16 * w + quad * 4 + r;
            if (gr < M) {
#pragma unroll
                for (int c = 0; c < NT; c++) {
                    int col = 16 * c + l16;
                    float v = acc[c][r] + bias[col];
                    if (act == 0) v = v > 0.f ? v : (__expf(v) - 1.f);
                    else          v = v > 0.f ? v : 0.01f * v;
                    outb[(size_t)gr * 64 + col] = f2b(v);
                }
            }
        }
    } else if (EPI == 2) {
#pragma unroll
        for (int r = 0; r < 4; r++) {
            int gr = row0 + 16 * w + quad * 4 + r;
            if (gr < M) {
                uint4 o0, o1;
                o0.x = (uint)f2b(acc[0][r])  | ((uint)f2b(acc[1][r])  << 16);
                o0.y = (uint)f2b(acc[2][r])  | ((uint)f2b(acc[3][r])  << 16);
                o0.z = (uint)f2b(acc[4][r])  | ((uint)f2b(acc[5][r])  << 16);
                o0.w = (uint)f2b(acc[6][r])  | ((uint)f2b(acc[7][r])  << 16);
                o1.x = (uint)f2b(acc[8][r])  | ((uint)f2b(acc[9][r])  << 16);
                o1.y = (uint)f2b(acc[10][r]) | ((uint)f2b(acc[11][r]) << 16);
                o1.z = (uint)f2b(acc[12][r]) | ((uint)f2b(acc[13][r]) << 16);
                o1.w = (uint)f2b(acc[14][r]) | ((uint)f2b(acc[15][r]) << 16);
                *(uint4*)(outb + (size_t)gr * 256 + l16 * 8) = o0;
                *(uint4*)(outb + (size_t)gr * 256 + 128 + l16 * 8) = o1;
            }
        }
    } else if (EPI == 3) {
        float av8[8];
#pragma unroll
        for (int c = 0; c < 8; c++)
            av8[c] = attn[(c >> 1) * 32 + (c & 1) * 16 + l16];
#pragma unroll
        for (int r = 0; r < 4; r++) {
            int gr = row0 + 16 * w + quad * 4 + r;
            if (gr < M) {
                int s = srcv[gr], d = dstv[gr];
                float xi8[8], xj8[8];
                unpack8(*(const uint4*)(xfull + (size_t)s * 256 + l16 * 8), xi8);
                unpack8(*(const uint4*)(xfull + (size_t)d * 256 + 128 + l16 * 8), xj8);
                float ph[4] = {0.f, 0.f, 0.f, 0.f};
#pragma unroll
                for (int c = 0; c < 8; c++) {
                    float f = lrelu02(acc[c][r] + xi8[c] + xj8[c]);
                    ph[c >> 1] = fmaf(f, av8[c], ph[c >> 1]);
                }
#pragma unroll
                for (int m = 1; m < 16; m <<= 1) {
#pragma unroll
                    for (int h = 0; h < 4; h++) ph[h] += __shfl_xor(ph[h], m);
                }
                if (l16 == 0)
                    *(float4*)(scv + (size_t)posv[gr] * 4) =
                        make_float4(ph[0], ph[1], ph[2], ph[3]);
            }
        }
    }
}

// ---------------------------------------------------------------------------
// CSR build: deg histogram -> hierarchical exclusive scan -> fused scatter
// ---------------------------------------------------------------------------
__global__ void k_count(const int* __restrict__ dst, int* __restrict__ deg, int E)
{
    for (int i = blockIdx.x * blockDim.x + threadIdx.x; i < E; i += gridDim.x * blockDim.x)
        atomicAdd(&deg[dst[i]], 1);
}

__global__ __launch_bounds__(256) void scan_local(
    const int* __restrict__ deg, int* __restrict__ rowptr, int* __restrict__ partials, int N)
{
    __shared__ int sd[256];
    int tid = threadIdx.x;
    int i = blockIdx.x * 256 + tid;
    int v = (i < N) ? deg[i] : 0;
    sd[tid] = v; __syncthreads();
#pragma unroll
    for (int off = 1; off < 256; off <<= 1) {
        int t = (tid >= off) ? sd[tid - off] : 0;
        __syncthreads();
        sd[tid] += t;
        __syncthreads();
    }
    if (i < N) rowptr[i] = sd[tid] - v;
    if (tid == 255) partials[blockIdx.x] = sd[255];
}

__global__ __launch_bounds__(256) void scan_partials(int* __restrict__ partials, int nb)
{
    __shared__ int sd[256];
    int tid = threadIdx.x;
    int v = (tid < nb) ? partials[tid] : 0;
    sd[tid] = v; __syncthreads();
#pragma unroll
    for (int off = 1; off < 256; off <<= 1) {
        int t = (tid >= off) ? sd[tid - off] : 0;
        __syncthreads();
        sd[tid] += t;
        __syncthreads();
    }
    if (tid < nb) partials[tid] = sd[tid] - v;
}

__global__ void scan_add(int* __restrict__ rowptr, const int* __restrict__ partials, int N, int E)
{
    int i = blockIdx.x * 256 + threadIdx.x;
    if (i < N) rowptr[i] += partials[i >> 8];
    if (i == 0) rowptr[N] = E;
}

// scatter + scalar permute fused: posv[i] = CSR position; srcp/m1p/m2p written there.
__global__ void k_scatter_perm(const int* __restrict__ dst, const int* __restrict__ rowptr,
                               int* __restrict__ cnt, const int* __restrict__ src,
                               const float* __restrict__ m1, const float* __restrict__ m2,
                               int* __restrict__ posv, int* __restrict__ srcp,
                               float* __restrict__ m1p, float* __restrict__ m2p, int E)
{
    for (int i = blockIdx.x * blockDim.x + threadIdx.x; i < E; i += gridDim.x * blockDim.x) {
        int d = dst[i];
        int p = rowptr[d] + atomicAdd(&cnt[d], 1);
        posv[i] = p;
        srcp[p] = src[i];
        m1p[p] = m1[i];
        m2p[p] = m2[i];
    }
}

__global__ void k_cvt(const float* __restrict__ in, ushort* __restrict__ out, int n)
{
    for (int i = blockIdx.x * blockDim.x + threadIdx.x; i < n; i += gridDim.x * blockDim.x)
        out[i] = f2b(in[i]);
}

// ---------------------------------------------------------------------------
// Weight prep, all 4 EGATs at once. egat e: 0=loc l0, 1=glob l0, 2=loc l1, 3=glob l1.
// ---------------------------------------------------------------------------
__global__ void k_prep_ninj_all(const float* __restrict__ loc_wni, const float* __restrict__ loc_wnj,
                                const float* __restrict__ glob_wni, const float* __restrict__ glob_wnj,
                                ushort* __restrict__ B)  // 4 x (256 x 64)
{
    int e = blockIdx.x >> 6;
    int idx = (blockIdx.x & 63) * 256 + threadIdx.x;  // 16384
    int layer = e >> 1, gl = e & 1;
    const float* wni = (gl ? glob_wni : loc_wni) + layer * 64 * 128;
    const float* wnj = (gl ? glob_wnj : loc_wnj) + layer * 64 * 128;
    int n = idx >> 6, k = idx & 63;
    float v = (n < 128) ? wni[k * 128 + n] : wnj[k * 128 + (n - 128)];
    B[e * 16384 + idx] = f2b(v);
}

__global__ void k_prep_we_all(const float* __restrict__ loc_we, const float* __restrict__ glob_we,
                              ushort* __restrict__ B)  // 4 slots; loc 128x32 (K pad), glob 128x64
{
    int b = blockIdx.x;
    int e, K, Kreal, idx;
    const float* we;
    if (b < 32) { int layer = b >> 4; e = layer * 2; K = 32; Kreal = 16;
                  we = loc_we + layer * 16 * 128; idx = (b & 15) * 256 + threadIdx.x; }
    else        { int layer = (b - 32) >> 5; e = layer * 2 + 1; K = 64; Kreal = 64;
                  we = glob_we + layer * 64 * 128; idx = ((b - 32) & 31) * 256 + threadIdx.x; }
    int n = idx / K, k = idx % K;
    B[e * 8192 + idx] = (k < Kreal) ? f2b(we[k * 128 + n]) : (ushort)0;
}

// W'[h*64+i, j] = sum_k wnode[i, h*64+k] * aggw[h*64+k, j]; stored transposed (64 x 256)
__global__ void k_fold_all(const float* __restrict__ loc_wnode, const float* __restrict__ agg1_w,
                           const float* __restrict__ glob_wnode, const float* __restrict__ agg2_w,
                           ushort* __restrict__ B)  // 4 x (64 x 256)
{
    int e = blockIdx.x >> 6;
    int idx = (blockIdx.x & 63) * 256 + threadIdx.x;  // 16384
    int layer = e >> 1, gl = e & 1;
    const float* wnode = (gl ? glob_wnode : loc_wnode) + layer * 64 * 256;
    const float* aggw  = (gl ? agg2_w : agg1_w) + layer * 256 * 64;
    int j = idx >> 8, col = idx & 255;
    int h = col >> 6, ii = col & 63;
    float s = 0.f;
#pragma unroll 8
    for (int k = 0; k < 64; k++)
        s = fmaf(wnode[ii * 256 + h * 64 + k], aggw[(h * 64 + k) * 64 + j], s);
    B[e * 16384 + j * 256 + col] = f2b(s);
}

// ---------------------------------------------------------------------------
// Light node kernel: softmax-sum (scores precomputed) + z aggregation.
// 4 edges in parallel (16 lanes each), no atomics. One wave per node.
// ---------------------------------------------------------------------------
__global__ __launch_bounds__(256) void node_fused(
    const float* __restrict__ scv,      // E x 4 fp32 (CSR order)
    const int* __restrict__ rowptr, const int* __restrict__ srcp,
    const float* __restrict__ maskp,
    const ushort* __restrict__ hsrc,    // N x 64 bf16 (layer input)
    ushort* __restrict__ zb)            // N x 256 bf16
{
    int tid = threadIdx.x, wv = tid >> 6, lane = tid & 63;
    int n = blockIdx.x * 4 + wv;
    int g = lane >> 4, sl = lane & 15;
    int beg = rowptr[n], end = rowptr[n + 1];
    float l4[4] = {0.f, 0.f, 0.f, 0.f};
    float acc[4][4] = {};
    for (int base = beg; base < end; base += 4) {
        int idx = base + g;
        bool valid = idx < end;
        int ic = valid ? idx : end - 1;
        int s = srcp[ic];
        float mk = valid ? maskp[ic] : 0.f;
        float p = scv[(size_t)ic * 4 + (sl & 3)];
        uint2 hvv = *(const uint2*)(hsrc + (size_t)s * 64 + sl * 4);
        float t = valid ? __expf(p) : 0.f;   // scores O(1): safe without max-sub
        float hv[4] = { b2f_lo(hvv.x), b2f_hi(hvv.x), b2f_lo(hvv.y), b2f_hi(hvv.y) };
#pragma unroll
        for (int h = 0; h < 4; h++) {
            float th = __shfl(t, (lane & 48) | h);
            l4[h] += th;
            float ae = th * mk;
#pragma unroll
            for (int c = 0; c < 4; c++) acc[h][c] = fmaf(ae, hv[c], acc[h][c]);
        }
    }
#pragma unroll
    for (int off = 16; off <= 32; off <<= 1) {
#pragma unroll
        for (int h = 0; h < 4; h++) {
            l4[h] += __shfl_xor(l4[h], off);
#pragma unroll
            for (int c = 0; c < 4; c++) acc[h][c] += __shfl_xor(acc[h][c], off);
        }
    }
    float inv = 1.f / (l4[g] + 1e-9f);
    uint2 o;
    o.x = (uint)f2b(acc[g][0] * inv) | ((uint)f2b(acc[g][1] * inv) << 16);
    o.y = (uint)f2b(acc[g][2] * inv) | ((uint)f2b(acc[g][3] * inv) << 16);
    *(uint2*)(zb + (size_t)n * 256 + g * 64 + sl * 4) = o;
}

// ---------------------------------------------------------------------------
// Final MLP heads. One wave per batch row.
// ---------------------------------------------------------------------------
__global__ __launch_bounds__(256) void final_ui(
    const ushort* __restrict__ s0, const ushort* __restrict__ s1,
    const int* __restrict__ uidx, const int* __restrict__ iidx,
    const float* __restrict__ w1, const float* __restrict__ b1,
    const float* __restrict__ w2, const float* __restrict__ b2, float* __restrict__ out)
{
    __shared__ float xs[4][256];
    int tid = threadIdx.x, wid = tid >> 6, lane = tid & 63;
    int r = (blockIdx.x << 2) + wid;
    int u = uidx[r], it = iidx[r];
    xs[wid][lane]       = b2f(s0[(size_t)u * 64 + lane]);
    xs[wid][64 + lane]  = b2f(s1[(size_t)u * 64 + lane]);
    xs[wid][128 + lane] = b2f(s0[(size_t)it * 64 + lane]);
    xs[wid][192 + lane] = b2f(s1[(size_t)it * 64 + lane]);
    __syncthreads();
    int c = lane << 1;
    float a0 = b1[c], a1 = b1[c + 1];
    for (int k = 0; k < 256; k++) {
        float xv = xs[wid][k];
        float2 wv = *(const float2*)(w1 + (size_t)k * 128 + c);
        a0 = fmaf(xv, wv.x, a0);
        a1 = fmaf(xv, wv.y, a1);
    }
    a0 = fmaxf(a0, 0.f);
    a1 = fmaxf(a1, 0.f);
    float2 w2v = *(const float2*)(w2 + c);
    float p = a0 * w2v.x + a1 * w2v.y;
#pragma unroll
    for (int mm = 1; mm < 64; mm <<= 1) p += __shfl_xor(p, mm);
    if (lane == 0) out[r] = 1.f / (1.f + __expf(-(p + b2[0])));
}

__global__ __launch_bounds__(256) void final_sg(
    const ushort* __restrict__ s0, const ushort* __restrict__ s1,
    const int* __restrict__ gidx,
    const float* __restrict__ w1, const float* __restrict__ b1,
    const float* __restrict__ w2, const float* __restrict__ b2, float* __restrict__ out)
{
    __shared__ float xs[4][128];
    int tid = threadIdx.x, wid = tid >> 6, lane = tid & 63;
    int r = (blockIdx.x << 2) + wid;
    int n = gidx[r];
    xs[wid][lane]      = b2f(s0[(size_t)n * 64 + lane]);
    xs[wid][64 + lane] = b2f(s1[(size_t)n * 64 + lane]);
    __syncthreads();
    int c = lane << 1;
    float a0 = b1[c], a1 = b1[c + 1];
    for (int k = 0; k < 128; k++) {
        float xv = xs[wid][k];
        float2 wv = *(const float2*)(w1 + (size_t)k * 128 + c);
        a0 = fmaf(xv, wv.x, a0);
        a1 = fmaf(xv, wv.y, a1);
    }
    a0 = fmaxf(a0, 0.f);
    a1 = fmaxf(a1, 0.f);
    float2 w2v = *(const float2*)(w2 + c);
    float p = a0 * w2v.x + a1 * w2v.y;
#pragma unroll
    for (int mm = 1; mm < 64; mm <<= 1) p += __shfl_xor(p, mm);
    if (lane == 0) out[r] = 1.f / (1.f + __expf(-(p + b2[0])));
}

// ---------------------------------------------------------------------------
extern "C" void kernel_launch(void* const* d_in, const int* in_sizes, int n_in,
                              void* d_out, int out_size, void* d_ws, size_t ws_size,
                              hipStream_t stream)
{
    const float* x       = (const float*)d_in[0];
    const float* efeat   = (const float*)d_in[1];
    const float* efeat2  = (const float*)d_in[2];
    const float* mask1   = (const float*)d_in[3];
    const float* mask2   = (const float*)d_in[4];
    const int*   src     = (const int*)d_in[5];
    const int*   dst     = (const int*)d_in[6];
    const int*   uidx    = (const int*)d_in[7];
    const int*   iidx    = (const int*)d_in[8];
    const int*   gidx    = (const int*)d_in[9];
    const float* loc_wni = (const float*)d_in[10];
    const float* loc_wnj = (const float*)d_in[11];
    const float* loc_we  = (const float*)d_in[12];
    const float* loc_attn= (const float*)d_in[13];
    const float* loc_wnode=(const float*)d_in[14];
    const float* agg1_w  = (const float*)d_in[15];
    const float* agg1_b  = (const float*)d_in[16];
    const float* glob_wni= (const float*)d_in[17];
    const float* glob_wnj= (const float*)d_in[18];
    const float* glob_we = (const float*)d_in[19];
    const float* glob_attn=(const float*)d_in[20];
    const float* glob_wnode=(const float*)d_in[21];
    const float* agg2_w  = (const float*)d_in[22];
    const float* agg2_b  = (const float*)d_in[23];
    const float* w1_ui   = (const float*)d_in[24];
    const float* b1_ui   = (const float*)d_in[25];
    const float* w1_sg   = (const float*)d_in[26];
    const float* b1_sg   = (const float*)d_in[27];
    const float* w2_ui   = (const float*)d_in[28];
    const float* b2_ui   = (const float*)d_in[29];
    const float* w2_sg   = (const float*)d_in[30];
    const float* b2_sg   = (const float*)d_in[31];

    // workspace carve (all offsets 256B-aligned)
    char* wsp = (char*)d_ws;
    auto carve = [&](size_t bytes) { char* p = wsp; wsp += (bytes + 255) & ~(size_t)255; return p; };
    ushort* xfull = (ushort*)carve((size_t)NN * 256 * 2);   // lane-permuted [xi|xj]
    ushort* zb    = (ushort*)carve((size_t)NN * 256 * 2);
    ushort* hb[5];
    for (int i = 0; i < 5; i++) hb[i] = (ushort*)carve((size_t)NN * 64 * 2);
    float*  scv   = (float*)carve((size_t)NE * 16);
    float*  m1p   = (float*)carve((size_t)NE * 4);
    float*  m2p   = (float*)carve((size_t)NE * 4);
    int*    srcp  = (int*)carve((size_t)NE * 4);
    ushort* Bninj = (ushort*)carve(4 * 16384 * 2);
    ushort* Bwe   = (ushort*)carve(4 * 8192 * 2);
    ushort* Bfold = (ushort*)carve(4 * 16384 * 2);
    int* deg      = (int*)carve(NN * 4);
    int* rowptr   = (int*)carve((NN + 4) * 4);
    int* partials = (int*)carve(256 * 4);
    int* posv     = (int*)carve(NE * 4);

    // ---- weight prep (state-independent) + CSR build + fused scatter ----
    k_prep_ninj_all<<<256, 256, 0, stream>>>(loc_wni, loc_wnj, glob_wni, glob_wnj, Bninj);
    k_prep_we_all<<<96, 256, 0, stream>>>(loc_we, glob_we, Bwe);
    k_fold_all<<<256, 256, 0, stream>>>(loc_wnode, agg1_w, glob_wnode, agg2_w, Bfold);
    hipMemsetAsync(deg, 0, NN * sizeof(int), stream);
    k_count<<<1280, 256, 0, stream>>>(dst, deg, NE);
    scan_local<<<196, 256, 0, stream>>>(deg, rowptr, partials, NN);
    scan_partials<<<1, 256, 0, stream>>>(partials, 196);
    scan_add<<<196, 256, 0, stream>>>(rowptr, partials, NN, NE);
    hipMemsetAsync(deg, 0, NN * sizeof(int), stream);
    k_scatter_perm<<<1280, 256, 0, stream>>>(dst, rowptr, deg, src, mask1, mask2,
                                             posv, srcp, m1p, m2p, NE);
    k_cvt<<<3200, 256, 0, stream>>>(x, hb[0], NN * 64);

    auto egat = [&](const ushort* hin, int e, const float* maskp, const float* attn,
                    const float* aggb, int act, ushort* hout) {
        int is_glob = e & 1;
        // xfull = [h@wni | h@wnj], lane-permuted layout (EPI 2)
        gemm_bf16<16, 2, 0><<<782, 256, 0, stream>>>(hin, 64, NN, 64, 64,
                                                     Bninj + e * 16384, xfull,
                                                     nullptr, 0, nullptr, nullptr,
                                                     nullptr, nullptr, nullptr, nullptr);
        // scores fused into e@we GEMM epilogue (EPI 3)
        if (is_glob)
            gemm_bf16<8, 3, 1><<<5000, 256, 0, stream>>>(efeat2, 64, NE, 64, 64,
                                                         Bwe + e * 8192, nullptr,
                                                         nullptr, 0, src, dst, posv,
                                                         xfull, attn, scv);
        else
            gemm_bf16<8, 3, 1><<<5000, 256, 0, stream>>>(efeat, 16, NE, 32, 16,
                                                         Bwe + e * 8192, nullptr,
                                                         nullptr, 0, src, dst, posv,
                                                         xfull, attn, scv);
        node_fused<<<12500, 256, 0, stream>>>(scv, rowptr, srcp, maskp, hin, zb);
        gemm_bf16<4, 1, 0><<<782, 256, 0, stream>>>(zb, 256, NN, 256, 256,
                                                    Bfold + e * 16384, hout,
                                                    aggb, act, nullptr, nullptr,
                                                    nullptr, nullptr, nullptr, nullptr);
    };

    egat(hb[0], 0, m1p, loc_attn,        agg1_b,      0, hb[1]);
    egat(hb[1], 1, m2p, glob_attn,       agg2_b,      1, hb[2]);
    egat(hb[2], 2, m1p, loc_attn + 128,  agg1_b + 64, 0, hb[3]);
    egat(hb[3], 3, m2p, glob_attn + 128, agg2_b + 64, 1, hb[4]);

    float* out = (float*)d_out;
    final_sg<<<BATCH / 4, 256, 0, stream>>>(hb[2], hb[4], gidx, w1_sg, b1_sg, w2_sg, b2_sg, out);
    final_ui<<<BATCH / 4, 256, 0, stream>>>(hb[1], hb[3], uidx, iidx, w1_ui, b1_ui, w2_ui, b2_ui, out + BATCH);
}

// Round 6
// 796.639 us; speedup vs baseline: 1.0950x; 1.0950x over previous
//
#include <hip/hip_runtime.h>
#include <math.h>

// EGAT GNN forward — round 6: round 5 structure (scores fused into e@we GEMM
// epilogue, no ewb buffer) with the node_fused shuffle-broadcast regression
// fixed: no in-loop ds_bpermute (16-way duplicate shuffles caused 1.2e7 LDS
// bank conflicts); scores read as broadcast float4, exp computed per-lane.
#define NN 50000      // N_NODES
#define NE 320000     // N_EDGES
#define BATCH 4096

typedef __bf16 bf16x8 __attribute__((ext_vector_type(8)));
typedef float floatx4 __attribute__((ext_vector_type(4)));
typedef unsigned short ushort;
typedef unsigned int uint;

__device__ __forceinline__ float lrelu02(float x) { return x > 0.f ? x : 0.2f * x; }
__device__ __forceinline__ float b2f(ushort h) { return __uint_as_float(((uint)h) << 16); }
__device__ __forceinline__ float b2f_lo(uint u) { return __uint_as_float(u << 16); }
__device__ __forceinline__ float b2f_hi(uint u) { return __uint_as_float(u & 0xffff0000u); }
__device__ __forceinline__ ushort f2b(float x) {
    uint u = __float_as_uint(x);
    return (ushort)((u + 0x7fffu + ((u >> 16) & 1u)) >> 16);  // RNE
}
__device__ __forceinline__ void unpack8(uint4 v, float* f) {
    f[0] = b2f_lo(v.x); f[1] = b2f_hi(v.x); f[2] = b2f_lo(v.y); f[3] = b2f_hi(v.y);
    f[4] = b2f_lo(v.z); f[5] = b2f_hi(v.z); f[6] = b2f_lo(v.w); f[7] = b2f_hi(v.w);
}

// ---------------------------------------------------------------------------
// bf16 MFMA GEMM, C tile 64 x 16*NT per block (4 waves). A (M x K, lda) bf16
// or fp32 (AF32: convert during staging; cols >= Kreal read 0).
// Bt = B^T ((16*NT) x K bf16). Epilogues:
//  EPI 1 (NT=4): +bias, act (0=ELU, 1=lrelu0.01), bf16 write row-major ld 64.
//  EPI 2 (NT=16): lane-permuted xfull write — col 16c+l16 stored at
//                 half*128 + l16*8 + (c&7), halves c<8 (xi) / c>=8 (xj).
//  EPI 3 (NT=8): score epilogue — gather xi[src],xj[dst] (permuted layout),
//                f=lrelu(ew+xi+xj), ph=sum f*attn per head, 16-lane reduce,
//                scatter float4 score to scv[posv[row]*4].
// ---------------------------------------------------------------------------
template <int NT, int EPI, int AF32>
__global__ __launch_bounds__(256) void gemm_bf16(
    const void* __restrict__ Av, int lda, int M, int K, int Kreal,
    const ushort* __restrict__ Bt,
    ushort* __restrict__ outb,
    const float* __restrict__ bias, int act,
    const int* __restrict__ srcv, const int* __restrict__ dstv,
    const int* __restrict__ posv,
    const ushort* __restrict__ xfull, const float* __restrict__ attn,
    float* __restrict__ scv)
{
    constexpr int NC = 16 * NT;
    __shared__ __align__(16) ushort As[64 * 32];
    __shared__ __align__(16) ushort Bs[NC * 32];
    const int tid = threadIdx.x;
    const int row0 = blockIdx.x << 6;
    const int w = tid >> 6, lane = tid & 63;
    const int quad = lane >> 4, l16 = lane & 15;
    const int arow = tid >> 2, akc = (tid & 3) << 3;

    floatx4 acc[NT];
#pragma unroll
    for (int c = 0; c < NT; c++)
#pragma unroll
        for (int r = 0; r < 4; r++) acc[c][r] = 0.f;

    for (int kt = 0; kt < K; kt += 32) {
        uint4 av = make_uint4(0u, 0u, 0u, 0u);
        if (AF32) {
            if (row0 + arow < M && kt + akc < Kreal) {
                const float* ap = (const float*)Av + (size_t)(row0 + arow) * lda + kt + akc;
                float4 f0 = *(const float4*)ap;
                float4 f1 = *(const float4*)(ap + 4);
                av.x = (uint)f2b(f0.x) | ((uint)f2b(f0.y) << 16);
                av.y = (uint)f2b(f0.z) | ((uint)f2b(f0.w) << 16);
                av.z = (uint)f2b(f1.x) | ((uint)f2b(f1.y) << 16);
                av.w = (uint)f2b(f1.z) | ((uint)f2b(f1.w) << 16);
            }
        } else {
            if (row0 + arow < M)
                av = *(const uint4*)((const ushort*)Av + (size_t)(row0 + arow) * lda + kt + akc);
        }
        *(uint4*)(As + arow * 32 + akc) = av;
#pragma unroll
        for (int it = 0; it < NT / 4; it++) {
            int idx = it * 256 + tid;
            int bn = idx >> 2, bkc = (idx & 3) << 3;
            *(uint4*)(Bs + bn * 32 + bkc) =
                *(const uint4*)(Bt + (size_t)bn * K + kt + bkc);
        }
        __syncthreads();
        bf16x8 af = *(const bf16x8*)(As + (16 * w + l16) * 32 + quad * 8);
#pragma unroll
        for (int c = 0; c < NT; c++) {
            bf16x8 bfv = *(const bf16x8*)(Bs + (16 * c + l16) * 32 + quad * 8);
            acc[c] = __builtin_amdgcn_mfma_f32_16x16x32_bf16(af, bfv, acc[c], 0, 0, 0);
        }
        __syncthreads();
    }

    if (EPI == 1) {
#pragma unroll
        for (int r = 0; r < 4; r++) {
            int gr = row0 + 16 * w + quad * 4 + r;
            if (gr < M) {
#pragma unroll
                for (int c = 0; c < NT; c++) {
                    int col = 16 * c + l16;
                    float v = acc[c][r] + bias[col];
                    if (act == 0) v = v > 0.f ? v : (__expf(v) - 1.f);
                    else          v = v > 0.f ? v : 0.01f * v;
                    outb[(size_t)gr * 64 + col] = f2b(v);
                }
            }
        }
    } else if (EPI == 2) {
#pragma unroll
        for (int r = 0; r < 4; r++) {
            int gr = row0 + 16 * w + quad * 4 + r;
            if (gr < M) {
                uint4 o0, o1;
                o0.x = (uint)f2b(acc[0][r])  | ((uint)f2b(acc[1][r])  << 16);
                o0.y = (uint)f2b(acc[2][r])  | ((uint)f2b(acc[3][r])  << 16);
                o0.z = (uint)f2b(acc[4][r])  | ((uint)f2b(acc[5][r])  << 16);
                o0.w = (uint)f2b(acc[6][r])  | ((uint)f2b(acc[7][r])  << 16);
                o1.x = (uint)f2b(acc[8][r])  | ((uint)f2b(acc[9][r])  << 16);
                o1.y = (uint)f2b(acc[10][r]) | ((uint)f2b(acc[11][r]) << 16);
                o1.z = (uint)f2b(acc[12][r]) | ((uint)f2b(acc[13][r]) << 16);
                o1.w = (uint)f2b(acc[14][r]) | ((uint)f2b(acc[15][r]) << 16);
                *(uint4*)(outb + (size_t)gr * 256 + l16 * 8) = o0;
                *(uint4*)(outb + (size_t)gr * 256 + 128 + l16 * 8) = o1;
            }
        }
    } else if (EPI == 3) {
        float av8[8];
#pragma unroll
        for (int c = 0; c < 8; c++)
            av8[c] = attn[(c >> 1) * 32 + (c & 1) * 16 + l16];
#pragma unroll
        for (int r = 0; r < 4; r++) {
            int gr = row0 + 16 * w + quad * 4 + r;
            if (gr < M) {
                int s = srcv[gr], d = dstv[gr];
                float xi8[8], xj8[8];
                unpack8(*(const uint4*)(xfull + (size_t)s * 256 + l16 * 8), xi8);
                unpack8(*(const uint4*)(xfull + (size_t)d * 256 + 128 + l16 * 8), xj8);
                float ph[4] = {0.f, 0.f, 0.f, 0.f};
#pragma unroll
                for (int c = 0; c < 8; c++) {
                    float f = lrelu02(acc[c][r] + xi8[c] + xj8[c]);
                    ph[c >> 1] = fmaf(f, av8[c], ph[c >> 1]);
                }
#pragma unroll
                for (int m = 1; m < 16; m <<= 1) {
#pragma unroll
                    for (int h = 0; h < 4; h++) ph[h] += __shfl_xor(ph[h], m);
                }
                if (l16 == 0)
                    *(float4*)(scv + (size_t)posv[gr] * 4) =
                        make_float4(ph[0], ph[1], ph[2], ph[3]);
            }
        }
    }
}

// ---------------------------------------------------------------------------
// CSR build: deg histogram -> hierarchical exclusive scan -> fused scatter
// ---------------------------------------------------------------------------
__global__ void k_count(const int* __restrict__ dst, int* __restrict__ deg, int E)
{
    for (int i = blockIdx.x * blockDim.x + threadIdx.x; i < E; i += gridDim.x * blockDim.x)
        atomicAdd(&deg[dst[i]], 1);
}

__global__ __launch_bounds__(256) void scan_local(
    const int* __restrict__ deg, int* __restrict__ rowptr, int* __restrict__ partials, int N)
{
    __shared__ int sd[256];
    int tid = threadIdx.x;
    int i = blockIdx.x * 256 + tid;
    int v = (i < N) ? deg[i] : 0;
    sd[tid] = v; __syncthreads();
#pragma unroll
    for (int off = 1; off < 256; off <<= 1) {
        int t = (tid >= off) ? sd[tid - off] : 0;
        __syncthreads();
        sd[tid] += t;
        __syncthreads();
    }
    if (i < N) rowptr[i] = sd[tid] - v;
    if (tid == 255) partials[blockIdx.x] = sd[255];
}

__global__ __launch_bounds__(256) void scan_partials(int* __restrict__ partials, int nb)
{
    __shared__ int sd[256];
    int tid = threadIdx.x;
    int v = (tid < nb) ? partials[tid] : 0;
    sd[tid] = v; __syncthreads();
#pragma unroll
    for (int off = 1; off < 256; off <<= 1) {
        int t = (tid >= off) ? sd[tid - off] : 0;
        __syncthreads();
        sd[tid] += t;
        __syncthreads();
    }
    if (tid < nb) partials[tid] = sd[tid] - v;
}

__global__ void scan_add(int* __restrict__ rowptr, const int* __restrict__ partials, int N, int E)
{
    int i = blockIdx.x * 256 + threadIdx.x;
    if (i < N) rowptr[i] += partials[i >> 8];
    if (i == 0) rowptr[N] = E;
}

// scatter + scalar permute fused: posv[i] = CSR position; srcp/m1p/m2p written there.
__global__ void k_scatter_perm(const int* __restrict__ dst, const int* __restrict__ rowptr,
                               int* __restrict__ cnt, const int* __restrict__ src,
                               const float* __restrict__ m1, const float* __restrict__ m2,
                               int* __restrict__ posv, int* __restrict__ srcp,
                               float* __restrict__ m1p, float* __restrict__ m2p, int E)
{
    for (int i = blockIdx.x * blockDim.x + threadIdx.x; i < E; i += gridDim.x * blockDim.x) {
        int d = dst[i];
        int p = rowptr[d] + atomicAdd(&cnt[d], 1);
        posv[i] = p;
        srcp[p] = src[i];
        m1p[p] = m1[i];
        m2p[p] = m2[i];
    }
}

__global__ void k_cvt(const float* __restrict__ in, ushort* __restrict__ out, int n)
{
    for (int i = blockIdx.x * blockDim.x + threadIdx.x; i < n; i += gridDim.x * blockDim.x)
        out[i] = f2b(in[i]);
}

// ---------------------------------------------------------------------------
// Weight prep, all 4 EGATs at once. egat e: 0=loc l0, 1=glob l0, 2=loc l1, 3=glob l1.
// ---------------------------------------------------------------------------
__global__ void k_prep_ninj_all(const float* __restrict__ loc_wni, const float* __restrict__ loc_wnj,
                                const float* __restrict__ glob_wni, const float* __restrict__ glob_wnj,
                                ushort* __restrict__ B)  // 4 x (256 x 64)
{
    int e = blockIdx.x >> 6;
    int idx = (blockIdx.x & 63) * 256 + threadIdx.x;  // 16384
    int layer = e >> 1, gl = e & 1;
    const float* wni = (gl ? glob_wni : loc_wni) + layer * 64 * 128;
    const float* wnj = (gl ? glob_wnj : loc_wnj) + layer * 64 * 128;
    int n = idx >> 6, k = idx & 63;
    float v = (n < 128) ? wni[k * 128 + n] : wnj[k * 128 + (n - 128)];
    B[e * 16384 + idx] = f2b(v);
}

__global__ void k_prep_we_all(const float* __restrict__ loc_we, const float* __restrict__ glob_we,
                              ushort* __restrict__ B)  // 4 slots; loc 128x32 (K pad), glob 128x64
{
    int b = blockIdx.x;
    int e, K, Kreal, idx;
    const float* we;
    if (b < 32) { int layer = b >> 4; e = layer * 2; K = 32; Kreal = 16;
                  we = loc_we + layer * 16 * 128; idx = (b & 15) * 256 + threadIdx.x; }
    else        { int layer = (b - 32) >> 5; e = layer * 2 + 1; K = 64; Kreal = 64;
                  we = glob_we + layer * 64 * 128; idx = ((b - 32) & 31) * 256 + threadIdx.x; }
    int n = idx / K, k = idx % K;
    B[e * 8192 + idx] = (k < Kreal) ? f2b(we[k * 128 + n]) : (ushort)0;
}

// W'[h*64+i, j] = sum_k wnode[i, h*64+k] * aggw[h*64+k, j]; stored transposed (64 x 256)
__global__ void k_fold_all(const float* __restrict__ loc_wnode, const float* __restrict__ agg1_w,
                           const float* __restrict__ glob_wnode, const float* __restrict__ agg2_w,
                           ushort* __restrict__ B)  // 4 x (64 x 256)
{
    int e = blockIdx.x >> 6;
    int idx = (blockIdx.x & 63) * 256 + threadIdx.x;  // 16384
    int layer = e >> 1, gl = e & 1;
    const float* wnode = (gl ? glob_wnode : loc_wnode) + layer * 64 * 256;
    const float* aggw  = (gl ? agg2_w : agg1_w) + layer * 256 * 64;
    int j = idx >> 8, col = idx & 255;
    int h = col >> 6, ii = col & 63;
    float s = 0.f;
#pragma unroll 8
    for (int k = 0; k < 64; k++)
        s = fmaf(wnode[ii * 256 + h * 64 + k], aggw[(h * 64 + k) * 64 + j], s);
    B[e * 16384 + j * 256 + col] = f2b(s);
}

// ---------------------------------------------------------------------------
// Light node kernel: softmax-sum (scores precomputed) + z aggregation.
// 4 edges in parallel (16 lanes each). NO in-loop shuffles: the group's 4
// scores arrive as one broadcast float4; exps computed per-lane (redundant but
// conflict-free). Cross-group combine via xor-16/32 butterfly at the end.
// One wave per node, no atomics.
// ---------------------------------------------------------------------------
__global__ __launch_bounds__(256) void node_fused(
    const float* __restrict__ scv,      // E x 4 fp32 (CSR order)
    const int* __restrict__ rowptr, const int* __restrict__ srcp,
    const float* __restrict__ maskp,
    const ushort* __restrict__ hsrc,    // N x 64 bf16 (layer input)
    ushort* __restrict__ zb)            // N x 256 bf16
{
    int tid = threadIdx.x, wv = tid >> 6, lane = tid & 63;
    int n = blockIdx.x * 4 + wv;
    int g = lane >> 4, sl = lane & 15;
    int beg = rowptr[n], end = rowptr[n + 1];
    float l4[4] = {0.f, 0.f, 0.f, 0.f};
    float acc[4][4] = {};
    for (int base = beg; base < end; base += 4) {
        int idx = base + g;
        bool valid = idx < end;
        int ic = valid ? idx : end - 1;
        int s = srcp[ic];
        float mk = valid ? maskp[ic] : 0.f;
        float4 s4 = *(const float4*)(scv + (size_t)ic * 4);   // broadcast in group
        uint2 hvv = *(const uint2*)(hsrc + (size_t)s * 64 + sl * 4);
        float t0 = valid ? __expf(s4.x) : 0.f;   // scores O(1): safe without max-sub
        float t1 = valid ? __expf(s4.y) : 0.f;
        float t2 = valid ? __expf(s4.z) : 0.f;
        float t3 = valid ? __expf(s4.w) : 0.f;
        l4[0] += t0; l4[1] += t1; l4[2] += t2; l4[3] += t3;
        float a0 = t0 * mk, a1 = t1 * mk, a2 = t2 * mk, a3 = t3 * mk;
        float hv[4] = { b2f_lo(hvv.x), b2f_hi(hvv.x), b2f_lo(hvv.y), b2f_hi(hvv.y) };
#pragma unroll
        for (int c = 0; c < 4; c++) {
            acc[0][c] = fmaf(a0, hv[c], acc[0][c]);
            acc[1][c] = fmaf(a1, hv[c], acc[1][c]);
            acc[2][c] = fmaf(a2, hv[c], acc[2][c]);
            acc[3][c] = fmaf(a3, hv[c], acc[3][c]);
        }
    }
    // combine the 4 groups (xor butterfly: distinct sources per lane, no dups)
#pragma unroll
    for (int off = 16; off <= 32; off <<= 1) {
#pragma unroll
        for (int h = 0; h < 4; h++) {
            l4[h] += __shfl_xor(l4[h], off);
#pragma unroll
            for (int c = 0; c < 4; c++) acc[h][c] += __shfl_xor(acc[h][c], off);
        }
    }
    float inv = 1.f / (l4[g] + 1e-9f);
    uint2 o;
    o.x = (uint)f2b(acc[g][0] * inv) | ((uint)f2b(acc[g][1] * inv) << 16);
    o.y = (uint)f2b(acc[g][2] * inv) | ((uint)f2b(acc[g][3] * inv) << 16);
    *(uint2*)(zb + (size_t)n * 256 + g * 64 + sl * 4) = o;
}

// ---------------------------------------------------------------------------
// Final MLP heads. One wave per batch row.
// ---------------------------------------------------------------------------
__global__ __launch_bounds__(256) void final_ui(
    const ushort* __restrict__ s0, const ushort* __restrict__ s1,
    const int* __restrict__ uidx, const int* __restrict__ iidx,
    const float* __restrict__ w1, const float* __restrict__ b1,
    const float* __restrict__ w2, const float* __restrict__ b2, float* __restrict__ out)
{
    __shared__ float xs[4][256];
    int tid = threadIdx.x, wid = tid >> 6, lane = tid & 63;
    int r = (blockIdx.x << 2) + wid;
    int u = uidx[r], it = iidx[r];
    xs[wid][lane]       = b2f(s0[(size_t)u * 64 + lane]);
    xs[wid][64 + lane]  = b2f(s1[(size_t)u * 64 + lane]);
    xs[wid][128 + lane] = b2f(s0[(size_t)it * 64 + lane]);
    xs[wid][192 + lane] = b2f(s1[(size_t)it * 64 + lane]);
    __syncthreads();
    int c = lane << 1;
    float a0 = b1[c], a1 = b1[c + 1];
    for (int k = 0; k < 256; k++) {
        float xv = xs[wid][k];
        float2 wv = *(const float2*)(w1 + (size_t)k * 128 + c);
        a0 = fmaf(xv, wv.x, a0);
        a1 = fmaf(xv, wv.y, a1);
    }
    a0 = fmaxf(a0, 0.f);
    a1 = fmaxf(a1, 0.f);
    float2 w2v = *(const float2*)(w2 + c);
    float p = a0 * w2v.x + a1 * w2v.y;
#pragma unroll
    for (int mm = 1; mm < 64; mm <<= 1) p += __shfl_xor(p, mm);
    if (lane == 0) out[r] = 1.f / (1.f + __expf(-(p + b2[0])));
}

__global__ __launch_bounds__(256) void final_sg(
    const ushort* __restrict__ s0, const ushort* __restrict__ s1,
    const int* __restrict__ gidx,
    const float* __restrict__ w1, const float* __restrict__ b1,
    const float* __restrict__ w2, const float* __restrict__ b2, float* __restrict__ out)
{
    __shared__ float xs[4][128];
    int tid = threadIdx.x, wid = tid >> 6, lane = tid & 63;
    int r = (blockIdx.x << 2) + wid;
    int n = gidx[r];
    xs[wid][lane]      = b2f(s0[(size_t)n * 64 + lane]);
    xs[wid][64 + lane] = b2f(s1[(size_t)n * 64 + lane]);
    __syncthreads();
    int c = lane << 1;
    float a0 = b1[c], a1 = b1[c + 1];
    for (int k = 0; k < 128; k++) {
        float xv = xs[wid][k];
        float2 wv = *(const float2*)(w1 + (size_t)k * 128 + c);
        a0 = fmaf(xv, wv.x, a0);
        a1 = fmaf(xv, wv.y, a1);
    }
    a0 = fmaxf(a0, 0.f);
    a1 = fmaxf(a1, 0.f);
    float2 w2v = *(const float2*)(w2 + c);
    float p = a0 * w2v.x + a1 * w2v.y;
#pragma unroll
    for (int mm = 1; mm < 64; mm <<= 1) p += __shfl_xor(p, mm);
    if (lane == 0) out[r] = 1.f / (1.f + __expf(-(p + b2[0])));
}

// ---------------------------------------------------------------------------
extern "C" void kernel_launch(void* const* d_in, const int* in_sizes, int n_in,
                              void* d_out, int out_size, void* d_ws, size_t ws_size,
                              hipStream_t stream)
{
    const float* x       = (const float*)d_in[0];
    const float* efeat   = (const float*)d_in[1];
    const float* efeat2  = (const float*)d_in[2];
    const float* mask1   = (const float*)d_in[3];
    const float* mask2   = (const float*)d_in[4];
    const int*   src     = (const int*)d_in[5];
    const int*   dst     = (const int*)d_in[6];
    const int*   uidx    = (const int*)d_in[7];
    const int*   iidx    = (const int*)d_in[8];
    const int*   gidx    = (const int*)d_in[9];
    const float* loc_wni = (const float*)d_in[10];
    const float* loc_wnj = (const float*)d_in[11];
    const float* loc_we  = (const float*)d_in[12];
    const float* loc_attn= (const float*)d_in[13];
    const float* loc_wnode=(const float*)d_in[14];
    const float* agg1_w  = (const float*)d_in[15];
    const float* agg1_b  = (const float*)d_in[16];
    const float* glob_wni= (const float*)d_in[17];
    const float* glob_wnj= (const float*)d_in[18];
    const float* glob_we = (const float*)d_in[19];
    const float* glob_attn=(const float*)d_in[20];
    const float* glob_wnode=(const float*)d_in[21];
    const float* agg2_w  = (const float*)d_in[22];
    const float* agg2_b  = (const float*)d_in[23];
    const float* w1_ui   = (const float*)d_in[24];
    const float* b1_ui   = (const float*)d_in[25];
    const float* w1_sg   = (const float*)d_in[26];
    const float* b1_sg   = (const float*)d_in[27];
    const float* w2_ui   = (const float*)d_in[28];
    const float* b2_ui   = (const float*)d_in[29];
    const float* w2_sg   = (const float*)d_in[30];
    const float* b2_sg   = (const float*)d_in[31];

    // workspace carve (all offsets 256B-aligned)
    char* wsp = (char*)d_ws;
    auto carve = [&](size_t bytes) { char* p = wsp; wsp += (bytes + 255) & ~(size_t)255; return p; };
    ushort* xfull = (ushort*)carve((size_t)NN * 256 * 2);   // lane-permuted [xi|xj]
    ushort* zb    = (ushort*)carve((size_t)NN * 256 * 2);
    ushort* hb[5];
    for (int i = 0; i < 5; i++) hb[i] = (ushort*)carve((size_t)NN * 64 * 2);
    float*  scv   = (float*)carve((size_t)NE * 16);
    float*  m1p   = (float*)carve((size_t)NE * 4);
    float*  m2p   = (float*)carve((size_t)NE * 4);
    int*    srcp  = (int*)carve((size_t)NE * 4);
    ushort* Bninj = (ushort*)carve(4 * 16384 * 2);
    ushort* Bwe   = (ushort*)carve(4 * 8192 * 2);
    ushort* Bfold = (ushort*)carve(4 * 16384 * 2);
    int* deg      = (int*)carve(NN * 4);
    int* rowptr   = (int*)carve((NN + 4) * 4);
    int* partials = (int*)carve(256 * 4);
    int* posv     = (int*)carve(NE * 4);

    // ---- weight prep (state-independent) + CSR build + fused scatter ----
    k_prep_ninj_all<<<256, 256, 0, stream>>>(loc_wni, loc_wnj, glob_wni, glob_wnj, Bninj);
    k_prep_we_all<<<96, 256, 0, stream>>>(loc_we, glob_we, Bwe);
    k_fold_all<<<256, 256, 0, stream>>>(loc_wnode, agg1_w, glob_wnode, agg2_w, Bfold);
    hipMemsetAsync(deg, 0, NN * sizeof(int), stream);
    k_count<<<1280, 256, 0, stream>>>(dst, deg, NE);
    scan_local<<<196, 256, 0, stream>>>(deg, rowptr, partials, NN);
    scan_partials<<<1, 256, 0, stream>>>(partials, 196);
    scan_add<<<196, 256, 0, stream>>>(rowptr, partials, NN, NE);
    hipMemsetAsync(deg, 0, NN * sizeof(int), stream);
    k_scatter_perm<<<1280, 256, 0, stream>>>(dst, rowptr, deg, src, mask1, mask2,
                                             posv, srcp, m1p, m2p, NE);
    k_cvt<<<3200, 256, 0, stream>>>(x, hb[0], NN * 64);

    auto egat = [&](const ushort* hin, int e, const float* maskp, const float* attn,
                    const float* aggb, int act, ushort* hout) {
        int is_glob = e & 1;
        // xfull = [h@wni | h@wnj], lane-permuted layout (EPI 2)
        gemm_bf16<16, 2, 0><<<782, 256, 0, stream>>>(hin, 64, NN, 64, 64,
                                                     Bninj + e * 16384, xfull,
                                                     nullptr, 0, nullptr, nullptr,
                                                     nullptr, nullptr, nullptr, nullptr);
        // scores fused into e@we GEMM epilogue (EPI 3)
        if (is_glob)
            gemm_bf16<8, 3, 1><<<5000, 256, 0, stream>>>(efeat2, 64, NE, 64, 64,
                                                         Bwe + e * 8192, nullptr,
                                                         nullptr, 0, src, dst, posv,
                                                         xfull, attn, scv);
        else
            gemm_bf16<8, 3, 1><<<5000, 256, 0, stream>>>(efeat, 16, NE, 32, 16,
                                                         Bwe + e * 8192, nullptr,
                                                         nullptr, 0, src, dst, posv,
                                                         xfull, attn, scv);
        node_fused<<<12500, 256, 0, stream>>>(scv, rowptr, srcp, maskp, hin, zb);
        gemm_bf16<4, 1, 0><<<782, 256, 0, stream>>>(zb, 256, NN, 256, 256,
                                                    Bfold + e * 16384, hout,
                                                    aggb, act, nullptr, nullptr,
                                                    nullptr, nullptr, nullptr, nullptr);
    };

    egat(hb[0], 0, m1p, loc_attn,        agg1_b,      0, hb[1]);
    egat(hb[1], 1, m2p, glob_attn,       agg2_b,      1, hb[2]);
    egat(hb[2], 2, m1p, loc_attn + 128,  agg1_b + 64, 0, hb[3]);
    egat(hb[3], 3, m2p, glob_attn + 128, agg2_b + 64, 1, hb[4]);

    float* out = (float*)d_out;
    final_sg<<<BATCH / 4, 256, 0, stream>>>(hb[2], hb[4], gidx, w1_sg, b1_sg, w2_sg, b2_sg, out);
    final_ui<<<BATCH / 4, 256, 0, stream>>>(hb[1], hb[3], uidx, iidx, w1_ui, b1_ui, w2_ui, b2_ui, out + BATCH);
}

// Round 7
// 646.702 us; speedup vs baseline: 1.3488x; 1.2318x over previous
//
#include <hip/hip_runtime.h>
#include <math.h>

// EGAT GNN forward — round 7: node_fused rebuilt with ZERO cross-lane ops.
// R5/R6 post-mortem: the end-of-kernel shuffle butterfly lowered to LDS-crossbar
// ds_swizzle (1.1e7 conflict cycles, ~20 us/dispatch); round 4's identical code
// lowered to DPP (0 conflicts) — codegen-unstable. Now: one 16-lane group owns a
// full node (all 4 heads), 16 groups/block; broadcast scores, coalesced hsrc
// rows, per-lane redundant exp, direct writes. No shuffles, no LDS.
#define NN 50000      // N_NODES
#define NE 320000     // N_EDGES
#define BATCH 4096

typedef __bf16 bf16x8 __attribute__((ext_vector_type(8)));
typedef float floatx4 __attribute__((ext_vector_type(4)));
typedef unsigned short ushort;
typedef unsigned int uint;

__device__ __forceinline__ float lrelu02(float x) { return x > 0.f ? x : 0.2f * x; }
__device__ __forceinline__ float b2f(ushort h) { return __uint_as_float(((uint)h) << 16); }
__device__ __forceinline__ float b2f_lo(uint u) { return __uint_as_float(u << 16); }
__device__ __forceinline__ float b2f_hi(uint u) { return __uint_as_float(u & 0xffff0000u); }
__device__ __forceinline__ ushort f2b(float x) {
    uint u = __float_as_uint(x);
    return (ushort)((u + 0x7fffu + ((u >> 16) & 1u)) >> 16);  // RNE
}
__device__ __forceinline__ void unpack8(uint4 v, float* f) {
    f[0] = b2f_lo(v.x); f[1] = b2f_hi(v.x); f[2] = b2f_lo(v.y); f[3] = b2f_hi(v.y);
    f[4] = b2f_lo(v.z); f[5] = b2f_hi(v.z); f[6] = b2f_lo(v.w); f[7] = b2f_hi(v.w);
}

// ---------------------------------------------------------------------------
// bf16 MFMA GEMM, C tile 64 x 16*NT per block (4 waves). A (M x K, lda) bf16
// or fp32 (AF32: convert during staging; cols >= Kreal read 0).
// Bt = B^T ((16*NT) x K bf16). Epilogues:
//  EPI 1 (NT=4): +bias, act (0=ELU, 1=lrelu0.01), bf16 write row-major ld 64.
//  EPI 2 (NT=16): lane-permuted xfull write — col 16c+l16 stored at
//                 half*128 + l16*8 + (c&7), halves c<8 (xi) / c>=8 (xj).
//  EPI 3 (NT=8): score epilogue — gather xi[src],xj[dst] (permuted layout),
//                f=lrelu(ew+xi+xj), ph=sum f*attn per head, 16-lane reduce,
//                scatter float4 score to scv[posv[row]*4].
// ---------------------------------------------------------------------------
template <int NT, int EPI, int AF32>
__global__ __launch_bounds__(256) void gemm_bf16(
    const void* __restrict__ Av, int lda, int M, int K, int Kreal,
    const ushort* __restrict__ Bt,
    ushort* __restrict__ outb,
    const float* __restrict__ bias, int act,
    const int* __restrict__ srcv, const int* __restrict__ dstv,
    const int* __restrict__ posv,
    const ushort* __restrict__ xfull, const float* __restrict__ attn,
    float* __restrict__ scv)
{
    constexpr int NC = 16 * NT;
    __shared__ __align__(16) ushort As[64 * 32];
    __shared__ __align__(16) ushort Bs[NC * 32];
    const int tid = threadIdx.x;
    const int row0 = blockIdx.x << 6;
    const int w = tid >> 6, lane = tid & 63;
    const int quad = lane >> 4, l16 = lane & 15;
    const int arow = tid >> 2, akc = (tid & 3) << 3;

    floatx4 acc[NT];
#pragma unroll
    for (int c = 0; c < NT; c++)
#pragma unroll
        for (int r = 0; r < 4; r++) acc[c][r] = 0.f;

    for (int kt = 0; kt < K; kt += 32) {
        uint4 av = make_uint4(0u, 0u, 0u, 0u);
        if (AF32) {
            if (row0 + arow < M && kt + akc < Kreal) {
                const float* ap = (const float*)Av + (size_t)(row0 + arow) * lda + kt + akc;
                float4 f0 = *(const float4*)ap;
                float4 f1 = *(const float4*)(ap + 4);
                av.x = (uint)f2b(f0.x) | ((uint)f2b(f0.y) << 16);
                av.y = (uint)f2b(f0.z) | ((uint)f2b(f0.w) << 16);
                av.z = (uint)f2b(f1.x) | ((uint)f2b(f1.y) << 16);
                av.w = (uint)f2b(f1.z) | ((uint)f2b(f1.w) << 16);
            }
        } else {
            if (row0 + arow < M)
                av = *(const uint4*)((const ushort*)Av + (size_t)(row0 + arow) * lda + kt + akc);
        }
        *(uint4*)(As + arow * 32 + akc) = av;
#pragma unroll
        for (int it = 0; it < NT / 4; it++) {
            int idx = it * 256 + tid;
            int bn = idx >> 2, bkc = (idx & 3) << 3;
            *(uint4*)(Bs + bn * 32 + bkc) =
                *(const uint4*)(Bt + (size_t)bn * K + kt + bkc);
        }
        __syncthreads();
        bf16x8 af = *(const bf16x8*)(As + (16 * w + l16) * 32 + quad * 8);
#pragma unroll
        for (int c = 0; c < NT; c++) {
            bf16x8 bfv = *(const bf16x8*)(Bs + (16 * c + l16) * 32 + quad * 8);
            acc[c] = __builtin_amdgcn_mfma_f32_16x16x32_bf16(af, bfv, acc[c], 0, 0, 0);
        }
        __syncthreads();
    }

    if (EPI == 1) {
#pragma unroll
        for (int r = 0; r < 4; r++) {
            int gr = row0 + 16 * w + quad * 4 + r;
            if (gr < M) {
#pragma unroll
                for (int c = 0; c < NT; c++) {
                    int col = 16 * c + l16;
                    float v = acc[c][r] + bias[col];
                    if (act == 0) v = v > 0.f ? v : (__expf(v) - 1.f);
                    else          v = v > 0.f ? v : 0.01f * v;
                    outb[(size_t)gr * 64 + col] = f2b(v);
                }
            }
        }
    } else if (EPI == 2) {
#pragma unroll
        for (int r = 0; r < 4; r++) {
            int gr = row0 + 16 * w + quad * 4 + r;
            if (gr < M) {
                uint4 o0, o1;
                o0.x = (uint)f2b(acc[0][r])  | ((uint)f2b(acc[1][r])  << 16);
                o0.y = (uint)f2b(acc[2][r])  | ((uint)f2b(acc[3][r])  << 16);
                o0.z = (uint)f2b(acc[4][r])  | ((uint)f2b(acc[5][r])  << 16);
                o0.w = (uint)f2b(acc[6][r])  | ((uint)f2b(acc[7][r])  << 16);
                o1.x = (uint)f2b(acc[8][r])  | ((uint)f2b(acc[9][r])  << 16);
                o1.y = (uint)f2b(acc[10][r]) | ((uint)f2b(acc[11][r]) << 16);
                o1.z = (uint)f2b(acc[12][r]) | ((uint)f2b(acc[13][r]) << 16);
                o1.w = (uint)f2b(acc[14][r]) | ((uint)f2b(acc[15][r]) << 16);
                *(uint4*)(outb + (size_t)gr * 256 + l16 * 8) = o0;
                *(uint4*)(outb + (size_t)gr * 256 + 128 + l16 * 8) = o1;
            }
        }
    } else if (EPI == 3) {
        float av8[8];
#pragma unroll
        for (int c = 0; c < 8; c++)
            av8[c] = attn[(c >> 1) * 32 + (c & 1) * 16 + l16];
#pragma unroll
        for (int r = 0; r < 4; r++) {
            int gr = row0 + 16 * w + quad * 4 + r;
            if (gr < M) {
                int s = srcv[gr], d = dstv[gr];
                float xi8[8], xj8[8];
                unpack8(*(const uint4*)(xfull + (size_t)s * 256 + l16 * 8), xi8);
                unpack8(*(const uint4*)(xfull + (size_t)d * 256 + 128 + l16 * 8), xj8);
                float ph[4] = {0.f, 0.f, 0.f, 0.f};
#pragma unroll
                for (int c = 0; c < 8; c++) {
                    float f = lrelu02(acc[c][r] + xi8[c] + xj8[c]);
                    ph[c >> 1] = fmaf(f, av8[c], ph[c >> 1]);
                }
#pragma unroll
                for (int m = 1; m < 16; m <<= 1) {
#pragma unroll
                    for (int h = 0; h < 4; h++) ph[h] += __shfl_xor(ph[h], m);
                }
                if (l16 == 0)
                    *(float4*)(scv + (size_t)posv[gr] * 4) =
                        make_float4(ph[0], ph[1], ph[2], ph[3]);
            }
        }
    }
}

// ---------------------------------------------------------------------------
// CSR build: deg histogram -> hierarchical exclusive scan -> fused scatter
// ---------------------------------------------------------------------------
__global__ void k_count(const int* __restrict__ dst, int* __restrict__ deg, int E)
{
    for (int i = blockIdx.x * blockDim.x + threadIdx.x; i < E; i += gridDim.x * blockDim.x)
        atomicAdd(&deg[dst[i]], 1);
}

__global__ __launch_bounds__(256) void scan_local(
    const int* __restrict__ deg, int* __restrict__ rowptr, int* __restrict__ partials, int N)
{
    __shared__ int sd[256];
    int tid = threadIdx.x;
    int i = blockIdx.x * 256 + tid;
    int v = (i < N) ? deg[i] : 0;
    sd[tid] = v; __syncthreads();
#pragma unroll
    for (int off = 1; off < 256; off <<= 1) {
        int t = (tid >= off) ? sd[tid - off] : 0;
        __syncthreads();
        sd[tid] += t;
        __syncthreads();
    }
    if (i < N) rowptr[i] = sd[tid] - v;
    if (tid == 255) partials[blockIdx.x] = sd[255];
}

__global__ __launch_bounds__(256) void scan_partials(int* __restrict__ partials, int nb)
{
    __shared__ int sd[256];
    int tid = threadIdx.x;
    int v = (tid < nb) ? partials[tid] : 0;
    sd[tid] = v; __syncthreads();
#pragma unroll
    for (int off = 1; off < 256; off <<= 1) {
        int t = (tid >= off) ? sd[tid - off] : 0;
        __syncthreads();
        sd[tid] += t;
        __syncthreads();
    }
    if (tid < nb) partials[tid] = sd[tid] - v;
}

__global__ void scan_add(int* __restrict__ rowptr, const int* __restrict__ partials, int N, int E)
{
    int i = blockIdx.x * 256 + threadIdx.x;
    if (i < N) rowptr[i] += partials[i >> 8];
    if (i == 0) rowptr[N] = E;
}

// scatter + scalar permute fused: posv[i] = CSR position; srcp/m1p/m2p written there.
__global__ void k_scatter_perm(const int* __restrict__ dst, const int* __restrict__ rowptr,
                               int* __restrict__ cnt, const int* __restrict__ src,
                               const float* __restrict__ m1, const float* __restrict__ m2,
                               int* __restrict__ posv, int* __restrict__ srcp,
                               float* __restrict__ m1p, float* __restrict__ m2p, int E)
{
    for (int i = blockIdx.x * blockDim.x + threadIdx.x; i < E; i += gridDim.x * blockDim.x) {
        int d = dst[i];
        int p = rowptr[d] + atomicAdd(&cnt[d], 1);
        posv[i] = p;
        srcp[p] = src[i];
        m1p[p] = m1[i];
        m2p[p] = m2[i];
    }
}

__global__ void k_cvt(const float* __restrict__ in, ushort* __restrict__ out, int n)
{
    for (int i = blockIdx.x * blockDim.x + threadIdx.x; i < n; i += gridDim.x * blockDim.x)
        out[i] = f2b(in[i]);
}

// ---------------------------------------------------------------------------
// Weight prep, all 4 EGATs at once. egat e: 0=loc l0, 1=glob l0, 2=loc l1, 3=glob l1.
// ---------------------------------------------------------------------------
__global__ void k_prep_ninj_all(const float* __restrict__ loc_wni, const float* __restrict__ loc_wnj,
                                const float* __restrict__ glob_wni, const float* __restrict__ glob_wnj,
                                ushort* __restrict__ B)  // 4 x (256 x 64)
{
    int e = blockIdx.x >> 6;
    int idx = (blockIdx.x & 63) * 256 + threadIdx.x;  // 16384
    int layer = e >> 1, gl = e & 1;
    const float* wni = (gl ? glob_wni : loc_wni) + layer * 64 * 128;
    const float* wnj = (gl ? glob_wnj : loc_wnj) + layer * 64 * 128;
    int n = idx >> 6, k = idx & 63;
    float v = (n < 128) ? wni[k * 128 + n] : wnj[k * 128 + (n - 128)];
    B[e * 16384 + idx] = f2b(v);
}

__global__ void k_prep_we_all(const float* __restrict__ loc_we, const float* __restrict__ glob_we,
                              ushort* __restrict__ B)  // 4 slots; loc 128x32 (K pad), glob 128x64
{
    int b = blockIdx.x;
    int e, K, Kreal, idx;
    const float* we;
    if (b < 32) { int layer = b >> 4; e = layer * 2; K = 32; Kreal = 16;
                  we = loc_we + layer * 16 * 128; idx = (b & 15) * 256 + threadIdx.x; }
    else        { int layer = (b - 32) >> 5; e = layer * 2 + 1; K = 64; Kreal = 64;
                  we = glob_we + layer * 64 * 128; idx = ((b - 32) & 31) * 256 + threadIdx.x; }
    int n = idx / K, k = idx % K;
    B[e * 8192 + idx] = (k < Kreal) ? f2b(we[k * 128 + n]) : (ushort)0;
}

// W'[h*64+i, j] = sum_k wnode[i, h*64+k] * aggw[h*64+k, j]; stored transposed (64 x 256)
__global__ void k_fold_all(const float* __restrict__ loc_wnode, const float* __restrict__ agg1_w,
                           const float* __restrict__ glob_wnode, const float* __restrict__ agg2_w,
                           ushort* __restrict__ B)  // 4 x (64 x 256)
{
    int e = blockIdx.x >> 6;
    int idx = (blockIdx.x & 63) * 256 + threadIdx.x;  // 16384
    int layer = e >> 1, gl = e & 1;
    const float* wnode = (gl ? glob_wnode : loc_wnode) + layer * 64 * 256;
    const float* aggw  = (gl ? agg2_w : agg1_w) + layer * 256 * 64;
    int j = idx >> 8, col = idx & 255;
    int h = col >> 6, ii = col & 63;
    float s = 0.f;
#pragma unroll 8
    for (int k = 0; k < 64; k++)
        s = fmaf(wnode[ii * 256 + h * 64 + k], aggw[(h * 64 + k) * 64 + j], s);
    B[e * 16384 + j * 256 + col] = f2b(s);
}

// ---------------------------------------------------------------------------
// Node kernel, zero cross-lane ops: one 16-lane group per node (all 4 heads),
// 16 groups per block, grid NN/16. Per edge: broadcast float4 score, scalar
// mask/src, one coalesced 128B hsrc row; per-lane redundant exp (cheap); each
// lane owns 4 h-columns x 4 heads, writes directly. No shuffles, no LDS.
// ---------------------------------------------------------------------------
__global__ __launch_bounds__(256) void node_fused(
    const float* __restrict__ scv,      // E x 4 fp32 (CSR order)
    const int* __restrict__ rowptr, const int* __restrict__ srcp,
    const float* __restrict__ maskp,
    const ushort* __restrict__ hsrc,    // N x 64 bf16 (layer input)
    ushort* __restrict__ zb)            // N x 256 bf16
{
    int tid = threadIdx.x;
    int n = (blockIdx.x << 4) | (tid >> 4);   // 16 groups/block, one node each
    int sl = tid & 15;
    int beg = rowptr[n], end = rowptr[n + 1];
    float l0 = 0.f, l1 = 0.f, l2 = 0.f, l3 = 0.f;
    float acc[4][4] = {};
    for (int i = beg; i < end; i++) {
        float4 s4 = *(const float4*)(scv + (size_t)i * 4);   // broadcast in group
        float mk = maskp[i];
        int s = srcp[i];
        uint2 hvv = *(const uint2*)(hsrc + (size_t)s * 64 + sl * 4);  // 128B/group
        float t0 = __expf(s4.x), t1 = __expf(s4.y), t2 = __expf(s4.z), t3 = __expf(s4.w);
        l0 += t0; l1 += t1; l2 += t2; l3 += t3;
        float a0 = t0 * mk, a1 = t1 * mk, a2 = t2 * mk, a3 = t3 * mk;
        float hv[4] = { b2f_lo(hvv.x), b2f_hi(hvv.x), b2f_lo(hvv.y), b2f_hi(hvv.y) };
#pragma unroll
        for (int c = 0; c < 4; c++) {
            acc[0][c] = fmaf(a0, hv[c], acc[0][c]);
            acc[1][c] = fmaf(a1, hv[c], acc[1][c]);
            acc[2][c] = fmaf(a2, hv[c], acc[2][c]);
            acc[3][c] = fmaf(a3, hv[c], acc[3][c]);
        }
    }
    float inv[4] = { 1.f / (l0 + 1e-9f), 1.f / (l1 + 1e-9f),
                     1.f / (l2 + 1e-9f), 1.f / (l3 + 1e-9f) };
#pragma unroll
    for (int h = 0; h < 4; h++) {
        uint2 o;
        o.x = (uint)f2b(acc[h][0] * inv[h]) | ((uint)f2b(acc[h][1] * inv[h]) << 16);
        o.y = (uint)f2b(acc[h][2] * inv[h]) | ((uint)f2b(acc[h][3] * inv[h]) << 16);
        *(uint2*)(zb + (size_t)n * 256 + h * 64 + sl * 4) = o;
    }
}

// ---------------------------------------------------------------------------
// Final MLP heads. One wave per batch row.
// ---------------------------------------------------------------------------
__global__ __launch_bounds__(256) void final_ui(
    const ushort* __restrict__ s0, const ushort* __restrict__ s1,
    const int* __restrict__ uidx, const int* __restrict__ iidx,
    const float* __restrict__ w1, const float* __restrict__ b1,
    const float* __restrict__ w2, const float* __restrict__ b2, float* __restrict__ out)
{
    __shared__ float xs[4][256];
    int tid = threadIdx.x, wid = tid >> 6, lane = tid & 63;
    int r = (blockIdx.x << 2) + wid;
    int u = uidx[r], it = iidx[r];
    xs[wid][lane]       = b2f(s0[(size_t)u * 64 + lane]);
    xs[wid][64 + lane]  = b2f(s1[(size_t)u * 64 + lane]);
    xs[wid][128 + lane] = b2f(s0[(size_t)it * 64 + lane]);
    xs[wid][192 + lane] = b2f(s1[(size_t)it * 64 + lane]);
    __syncthreads();
    int c = lane << 1;
    float a0 = b1[c], a1 = b1[c + 1];
    for (int k = 0; k < 256; k++) {
        float xv = xs[wid][k];
        float2 wv = *(const float2*)(w1 + (size_t)k * 128 + c);
        a0 = fmaf(xv, wv.x, a0);
        a1 = fmaf(xv, wv.y, a1);
    }
    a0 = fmaxf(a0, 0.f);
    a1 = fmaxf(a1, 0.f);
    float2 w2v = *(const float2*)(w2 + c);
    float p = a0 * w2v.x + a1 * w2v.y;
#pragma unroll
    for (int mm = 1; mm < 64; mm <<= 1) p += __shfl_xor(p, mm);
    if (lane == 0) out[r] = 1.f / (1.f + __expf(-(p + b2[0])));
}

__global__ __launch_bounds__(256) void final_sg(
    const ushort* __restrict__ s0, const ushort* __restrict__ s1,
    const int* __restrict__ gidx,
    const float* __restrict__ w1, const float* __restrict__ b1,
    const float* __restrict__ w2, const float* __restrict__ b2, float* __restrict__ out)
{
    __shared__ float xs[4][128];
    int tid = threadIdx.x, wid = tid >> 6, lane = tid & 63;
    int r = (blockIdx.x << 2) + wid;
    int n = gidx[r];
    xs[wid][lane]      = b2f(s0[(size_t)n * 64 + lane]);
    xs[wid][64 + lane] = b2f(s1[(size_t)n * 64 + lane]);
    __syncthreads();
    int c = lane << 1;
    float a0 = b1[c], a1 = b1[c + 1];
    for (int k = 0; k < 128; k++) {
        float xv = xs[wid][k];
        float2 wv = *(const float2*)(w1 + (size_t)k * 128 + c);
        a0 = fmaf(xv, wv.x, a0);
        a1 = fmaf(xv, wv.y, a1);
    }
    a0 = fmaxf(a0, 0.f);
    a1 = fmaxf(a1, 0.f);
    float2 w2v = *(const float2*)(w2 + c);
    float p = a0 * w2v.x + a1 * w2v.y;
#pragma unroll
    for (int mm = 1; mm < 64; mm <<= 1) p += __shfl_xor(p, mm);
    if (lane == 0) out[r] = 1.f / (1.f + __expf(-(p + b2[0])));
}

// ---------------------------------------------------------------------------
extern "C" void kernel_launch(void* const* d_in, const int* in_sizes, int n_in,
                              void* d_out, int out_size, void* d_ws, size_t ws_size,
                              hipStream_t stream)
{
    const float* x       = (const float*)d_in[0];
    const float* efeat   = (const float*)d_in[1];
    const float* efeat2  = (const float*)d_in[2];
    const float* mask1   = (const float*)d_in[3];
    const float* mask2   = (const float*)d_in[4];
    const int*   src     = (const int*)d_in[5];
    const int*   dst     = (const int*)d_in[6];
    const int*   uidx    = (const int*)d_in[7];
    const int*   iidx    = (const int*)d_in[8];
    const int*   gidx    = (const int*)d_in[9];
    const float* loc_wni = (const float*)d_in[10];
    const float* loc_wnj = (const float*)d_in[11];
    const float* loc_we  = (const float*)d_in[12];
    const float* loc_attn= (const float*)d_in[13];
    const float* loc_wnode=(const float*)d_in[14];
    const float* agg1_w  = (const float*)d_in[15];
    const float* agg1_b  = (const float*)d_in[16];
    const float* glob_wni= (const float*)d_in[17];
    const float* glob_wnj= (const float*)d_in[18];
    const float* glob_we = (const float*)d_in[19];
    const float* glob_attn=(const float*)d_in[20];
    const float* glob_wnode=(const float*)d_in[21];
    const float* agg2_w  = (const float*)d_in[22];
    const float* agg2_b  = (const float*)d_in[23];
    const float* w1_ui   = (const float*)d_in[24];
    const float* b1_ui   = (const float*)d_in[25];
    const float* w1_sg   = (const float*)d_in[26];
    const float* b1_sg   = (const float*)d_in[27];
    const float* w2_ui   = (const float*)d_in[28];
    const float* b2_ui   = (const float*)d_in[29];
    const float* w2_sg   = (const float*)d_in[30];
    const float* b2_sg   = (const float*)d_in[31];

    // workspace carve (all offsets 256B-aligned)
    char* wsp = (char*)d_ws;
    auto carve = [&](size_t bytes) { char* p = wsp; wsp += (bytes + 255) & ~(size_t)255; return p; };
    ushort* xfull = (ushort*)carve((size_t)NN * 256 * 2);   // lane-permuted [xi|xj]
    ushort* zb    = (ushort*)carve((size_t)NN * 256 * 2);
    ushort* hb[5];
    for (int i = 0; i < 5; i++) hb[i] = (ushort*)carve((size_t)NN * 64 * 2);
    float*  scv   = (float*)carve((size_t)NE * 16);
    float*  m1p   = (float*)carve((size_t)NE * 4);
    float*  m2p   = (float*)carve((size_t)NE * 4);
    int*    srcp  = (int*)carve((size_t)NE * 4);
    ushort* Bninj = (ushort*)carve(4 * 16384 * 2);
    ushort* Bwe   = (ushort*)carve(4 * 8192 * 2);
    ushort* Bfold = (ushort*)carve(4 * 16384 * 2);
    int* deg      = (int*)carve(NN * 4);
    int* rowptr   = (int*)carve((NN + 4) * 4);
    int* partials = (int*)carve(256 * 4);
    int* posv     = (int*)carve(NE * 4);

    // ---- weight prep (state-independent) + CSR build + fused scatter ----
    k_prep_ninj_all<<<256, 256, 0, stream>>>(loc_wni, loc_wnj, glob_wni, glob_wnj, Bninj);
    k_prep_we_all<<<96, 256, 0, stream>>>(loc_we, glob_we, Bwe);
    k_fold_all<<<256, 256, 0, stream>>>(loc_wnode, agg1_w, glob_wnode, agg2_w, Bfold);
    hipMemsetAsync(deg, 0, NN * sizeof(int), stream);
    k_count<<<1280, 256, 0, stream>>>(dst, deg, NE);
    scan_local<<<196, 256, 0, stream>>>(deg, rowptr, partials, NN);
    scan_partials<<<1, 256, 0, stream>>>(partials, 196);
    scan_add<<<196, 256, 0, stream>>>(rowptr, partials, NN, NE);
    hipMemsetAsync(deg, 0, NN * sizeof(int), stream);
    k_scatter_perm<<<1280, 256, 0, stream>>>(dst, rowptr, deg, src, mask1, mask2,
                                             posv, srcp, m1p, m2p, NE);
    k_cvt<<<3200, 256, 0, stream>>>(x, hb[0], NN * 64);

    auto egat = [&](const ushort* hin, int e, const float* maskp, const float* attn,
                    const float* aggb, int act, ushort* hout) {
        int is_glob = e & 1;
        // xfull = [h@wni | h@wnj], lane-permuted layout (EPI 2)
        gemm_bf16<16, 2, 0><<<782, 256, 0, stream>>>(hin, 64, NN, 64, 64,
                                                     Bninj + e * 16384, xfull,
                                                     nullptr, 0, nullptr, nullptr,
                                                     nullptr, nullptr, nullptr, nullptr);
        // scores fused into e@we GEMM epilogue (EPI 3)
        if (is_glob)
            gemm_bf16<8, 3, 1><<<5000, 256, 0, stream>>>(efeat2, 64, NE, 64, 64,
                                                         Bwe + e * 8192, nullptr,
                                                         nullptr, 0, src, dst, posv,
                                                         xfull, attn, scv);
        else
            gemm_bf16<8, 3, 1><<<5000, 256, 0, stream>>>(efeat, 16, NE, 32, 16,
                                                         Bwe + e * 8192, nullptr,
                                                         nullptr, 0, src, dst, posv,
                                                         xfull, attn, scv);
        node_fused<<<NN / 16, 256, 0, stream>>>(scv, rowptr, srcp, maskp, hin, zb);
        gemm_bf16<4, 1, 0><<<782, 256, 0, stream>>>(zb, 256, NN, 256, 256,
                                                    Bfold + e * 16384, hout,
                                                    aggb, act, nullptr, nullptr,
                                                    nullptr, nullptr, nullptr, nullptr);
    };

    egat(hb[0], 0, m1p, loc_attn,        agg1_b,      0, hb[1]);
    egat(hb[1], 1, m2p, glob_attn,       agg2_b,      1, hb[2]);
    egat(hb[2], 2, m1p, loc_attn + 128,  agg1_b + 64, 0, hb[3]);
    egat(hb[3], 3, m2p, glob_attn + 128, agg2_b + 64, 1, hb[4]);

    float* out = (float*)d_out;
    final_sg<<<BATCH / 4, 256, 0, stream>>>(hb[2], hb[4], gidx, w1_sg, b1_sg, w2_sg, b2_sg, out);
    final_ui<<<BATCH / 4, 256, 0, stream>>>(hb[1], hb[3], uidx, iidx, w1_ui, b1_ui, w2_ui, b2_ui, out + BATCH);
}

// Round 8
// 640.006 us; speedup vs baseline: 1.3630x; 1.0105x over previous
//
#include <hip/hip_runtime.h>
#include <math.h>

// EGAT GNN forward — round 8: score GEMM processes edges in CSR order.
// A-row gather via eidx[] in staging (scattered 256B reads, throughput-friendly);
// epilogue xj[dst] becomes sequential (L1 reuse, consecutive rows share dst),
// score writes coalesced (posv deleted). node_fused edge loop unrolled x2.
#define NN 50000      // N_NODES
#define NE 320000     // N_EDGES
#define BATCH 4096

typedef __bf16 bf16x8 __attribute__((ext_vector_type(8)));
typedef float floatx4 __attribute__((ext_vector_type(4)));
typedef unsigned short ushort;
typedef unsigned int uint;

__device__ __forceinline__ float lrelu02(float x) { return x > 0.f ? x : 0.2f * x; }
__device__ __forceinline__ float b2f(ushort h) { return __uint_as_float(((uint)h) << 16); }
__device__ __forceinline__ float b2f_lo(uint u) { return __uint_as_float(u << 16); }
__device__ __forceinline__ float b2f_hi(uint u) { return __uint_as_float(u & 0xffff0000u); }
__device__ __forceinline__ ushort f2b(float x) {
    uint u = __float_as_uint(x);
    return (ushort)((u + 0x7fffu + ((u >> 16) & 1u)) >> 16);  // RNE
}
__device__ __forceinline__ void unpack8(uint4 v, float* f) {
    f[0] = b2f_lo(v.x); f[1] = b2f_hi(v.x); f[2] = b2f_lo(v.y); f[3] = b2f_hi(v.y);
    f[4] = b2f_lo(v.z); f[5] = b2f_hi(v.z); f[6] = b2f_lo(v.w); f[7] = b2f_hi(v.w);
}

// ---------------------------------------------------------------------------
// bf16 MFMA GEMM, C tile 64 x 16*NT per block (4 waves). A (M x K, lda) bf16
// or fp32 (AF32: convert during staging; cols >= Kreal read 0). If ridx !=
// nullptr, A row gr is gathered from ridx[gr] (CSR->orig indirection).
// Bt = B^T ((16*NT) x K bf16). Epilogues:
//  EPI 1 (NT=4): +bias, act (0=ELU, 1=lrelu0.01), bf16 write row-major ld 64.
//  EPI 2 (NT=16): lane-permuted xfull write — col 16c+l16 stored at
//                 half*128 + l16*8 + (c&7), halves c<8 (xi) / c>=8 (xj).
//  EPI 3 (NT=8): score epilogue, rows = CSR positions — gather xi[srcv[gr]],
//                xj[dstv[gr]] (dst sequential in CSR order -> L1 reuse),
//                f=lrelu(ew+xi+xj), ph=sum f*attn per head, 16-lane reduce,
//                coalesced float4 score write to scv[gr*4].
// ---------------------------------------------------------------------------
template <int NT, int EPI, int AF32>
__global__ __launch_bounds__(256) void gemm_bf16(
    const void* __restrict__ Av, int lda, int M, int K, int Kreal,
    const ushort* __restrict__ Bt,
    ushort* __restrict__ outb,
    const float* __restrict__ bias, int act,
    const int* __restrict__ ridx,
    const int* __restrict__ srcv, const int* __restrict__ dstv,
    const ushort* __restrict__ xfull, const float* __restrict__ attn,
    float* __restrict__ scv)
{
    constexpr int NC = 16 * NT;
    __shared__ __align__(16) ushort As[64 * 32];
    __shared__ __align__(16) ushort Bs[NC * 32];
    const int tid = threadIdx.x;
    const int row0 = blockIdx.x << 6;
    const int w = tid >> 6, lane = tid & 63;
    const int quad = lane >> 4, l16 = lane & 15;
    const int arow = tid >> 2, akc = (tid & 3) << 3;
    // hoisted A-row indirection (4 staging threads share arow -> broadcast load)
    int agrow = -1;
    if (row0 + arow < M) agrow = ridx ? ridx[row0 + arow] : (row0 + arow);

    floatx4 acc[NT];
#pragma unroll
    for (int c = 0; c < NT; c++)
#pragma unroll
        for (int r = 0; r < 4; r++) acc[c][r] = 0.f;

    for (int kt = 0; kt < K; kt += 32) {
        uint4 av = make_uint4(0u, 0u, 0u, 0u);
        if (AF32) {
            if (agrow >= 0 && kt + akc < Kreal) {
                const float* ap = (const float*)Av + (size_t)agrow * lda + kt + akc;
                float4 f0 = *(const float4*)ap;
                float4 f1 = *(const float4*)(ap + 4);
                av.x = (uint)f2b(f0.x) | ((uint)f2b(f0.y) << 16);
                av.y = (uint)f2b(f0.z) | ((uint)f2b(f0.w) << 16);
                av.z = (uint)f2b(f1.x) | ((uint)f2b(f1.y) << 16);
                av.w = (uint)f2b(f1.z) | ((uint)f2b(f1.w) << 16);
            }
        } else {
            if (agrow >= 0)
                av = *(const uint4*)((const ushort*)Av + (size_t)agrow * lda + kt + akc);
        }
        *(uint4*)(As + arow * 32 + akc) = av;
#pragma unroll
        for (int it = 0; it < NT / 4; it++) {
            int idx = it * 256 + tid;
            int bn = idx >> 2, bkc = (idx & 3) << 3;
            *(uint4*)(Bs + bn * 32 + bkc) =
                *(const uint4*)(Bt + (size_t)bn * K + kt + bkc);
        }
        __syncthreads();
        bf16x8 af = *(const bf16x8*)(As + (16 * w + l16) * 32 + quad * 8);
#pragma unroll
        for (int c = 0; c < NT; c++) {
            bf16x8 bfv = *(const bf16x8*)(Bs + (16 * c + l16) * 32 + quad * 8);
            acc[c] = __builtin_amdgcn_mfma_f32_16x16x32_bf16(af, bfv, acc[c], 0, 0, 0);
        }
        __syncthreads();
    }

    if (EPI == 1) {
#pragma unroll
        for (int r = 0; r < 4; r++) {
            int gr = row0 + 16 * w + quad * 4 + r;
            if (gr < M) {
#pragma unroll
                for (int c = 0; c < NT; c++) {
                    int col = 16 * c + l16;
                    float v = acc[c][r] + bias[col];
                    if (act == 0) v = v > 0.f ? v : (__expf(v) - 1.f);
                    else          v = v > 0.f ? v : 0.01f * v;
                    outb[(size_t)gr * 64 + col] = f2b(v);
                }
            }
        }
    } else if (EPI == 2) {
#pragma unroll
        for (int r = 0; r < 4; r++) {
            int gr = row0 + 16 * w + quad * 4 + r;
            if (gr < M) {
                uint4 o0, o1;
                o0.x = (uint)f2b(acc[0][r])  | ((uint)f2b(acc[1][r])  << 16);
                o0.y = (uint)f2b(acc[2][r])  | ((uint)f2b(acc[3][r])  << 16);
                o0.z = (uint)f2b(acc[4][r])  | ((uint)f2b(acc[5][r])  << 16);
                o0.w = (uint)f2b(acc[6][r])  | ((uint)f2b(acc[7][r])  << 16);
                o1.x = (uint)f2b(acc[8][r])  | ((uint)f2b(acc[9][r])  << 16);
                o1.y = (uint)f2b(acc[10][r]) | ((uint)f2b(acc[11][r]) << 16);
                o1.z = (uint)f2b(acc[12][r]) | ((uint)f2b(acc[13][r]) << 16);
                o1.w = (uint)f2b(acc[14][r]) | ((uint)f2b(acc[15][r]) << 16);
                *(uint4*)(outb + (size_t)gr * 256 + l16 * 8) = o0;
                *(uint4*)(outb + (size_t)gr * 256 + 128 + l16 * 8) = o1;
            }
        }
    } else if (EPI == 3) {
        float av8[8];
#pragma unroll
        for (int c = 0; c < 8; c++)
            av8[c] = attn[(c >> 1) * 32 + (c & 1) * 16 + l16];
#pragma unroll
        for (int r = 0; r < 4; r++) {
            int gr = row0 + 16 * w + quad * 4 + r;
            if (gr < M) {
                int s = srcv[gr], d = dstv[gr];
                float xi8[8], xj8[8];
                unpack8(*(const uint4*)(xfull + (size_t)s * 256 + l16 * 8), xi8);
                unpack8(*(const uint4*)(xfull + (size_t)d * 256 + 128 + l16 * 8), xj8);
                float ph[4] = {0.f, 0.f, 0.f, 0.f};
#pragma unroll
                for (int c = 0; c < 8; c++) {
                    float f = lrelu02(acc[c][r] + xi8[c] + xj8[c]);
                    ph[c >> 1] = fmaf(f, av8[c], ph[c >> 1]);
                }
#pragma unroll
                for (int m = 1; m < 16; m <<= 1) {
#pragma unroll
                    for (int h = 0; h < 4; h++) ph[h] += __shfl_xor(ph[h], m);
                }
                if (l16 == 0)
                    *(float4*)(scv + (size_t)gr * 4) =
                        make_float4(ph[0], ph[1], ph[2], ph[3]);
            }
        }
    }
}

// ---------------------------------------------------------------------------
// CSR build: deg histogram -> hierarchical exclusive scan -> fused scatter
// ---------------------------------------------------------------------------
__global__ void k_count(const int* __restrict__ dst, int* __restrict__ deg, int E)
{
    for (int i = blockIdx.x * blockDim.x + threadIdx.x; i < E; i += gridDim.x * blockDim.x)
        atomicAdd(&deg[dst[i]], 1);
}

__global__ __launch_bounds__(256) void scan_local(
    const int* __restrict__ deg, int* __restrict__ rowptr, int* __restrict__ partials, int N)
{
    __shared__ int sd[256];
    int tid = threadIdx.x;
    int i = blockIdx.x * 256 + tid;
    int v = (i < N) ? deg[i] : 0;
    sd[tid] = v; __syncthreads();
#pragma unroll
    for (int off = 1; off < 256; off <<= 1) {
        int t = (tid >= off) ? sd[tid - off] : 0;
        __syncthreads();
        sd[tid] += t;
        __syncthreads();
    }
    if (i < N) rowptr[i] = sd[tid] - v;
    if (tid == 255) partials[blockIdx.x] = sd[255];
}

__global__ __launch_bounds__(256) void scan_partials(int* __restrict__ partials, int nb)
{
    __shared__ int sd[256];
    int tid = threadIdx.x;
    int v = (tid < nb) ? partials[tid] : 0;
    sd[tid] = v; __syncthreads();
#pragma unroll
    for (int off = 1; off < 256; off <<= 1) {
        int t = (tid >= off) ? sd[tid - off] : 0;
        __syncthreads();
        sd[tid] += t;
        __syncthreads();
    }
    if (tid < nb) partials[tid] = sd[tid] - v;
}

__global__ void scan_add(int* __restrict__ rowptr, const int* __restrict__ partials, int N, int E)
{
    int i = blockIdx.x * 256 + threadIdx.x;
    if (i < N) rowptr[i] += partials[i >> 8];
    if (i == 0) rowptr[N] = E;
}

// scatter + permute fused: p = CSR position of edge i; emit srcp/dstp/eidx/m1p/m2p.
__global__ void k_scatter_perm(const int* __restrict__ dst, const int* __restrict__ rowptr,
                               int* __restrict__ cnt, const int* __restrict__ src,
                               const float* __restrict__ m1, const float* __restrict__ m2,
                               int* __restrict__ srcp, int* __restrict__ dstp,
                               int* __restrict__ eidx,
                               float* __restrict__ m1p, float* __restrict__ m2p, int E)
{
    for (int i = blockIdx.x * blockDim.x + threadIdx.x; i < E; i += gridDim.x * blockDim.x) {
        int d = dst[i];
        int p = rowptr[d] + atomicAdd(&cnt[d], 1);
        srcp[p] = src[i];
        dstp[p] = d;
        eidx[p] = i;
        m1p[p] = m1[i];
        m2p[p] = m2[i];
    }
}

__global__ void k_cvt(const float* __restrict__ in, ushort* __restrict__ out, int n)
{
    for (int i = blockIdx.x * blockDim.x + threadIdx.x; i < n; i += gridDim.x * blockDim.x)
        out[i] = f2b(in[i]);
}

// ---------------------------------------------------------------------------
// Weight prep, all 4 EGATs at once. egat e: 0=loc l0, 1=glob l0, 2=loc l1, 3=glob l1.
// ---------------------------------------------------------------------------
__global__ void k_prep_ninj_all(const float* __restrict__ loc_wni, const float* __restrict__ loc_wnj,
                                const float* __restrict__ glob_wni, const float* __restrict__ glob_wnj,
                                ushort* __restrict__ B)  // 4 x (256 x 64)
{
    int e = blockIdx.x >> 6;
    int idx = (blockIdx.x & 63) * 256 + threadIdx.x;  // 16384
    int layer = e >> 1, gl = e & 1;
    const float* wni = (gl ? glob_wni : loc_wni) + layer * 64 * 128;
    const float* wnj = (gl ? glob_wnj : loc_wnj) + layer * 64 * 128;
    int n = idx >> 6, k = idx & 63;
    float v = (n < 128) ? wni[k * 128 + n] : wnj[k * 128 + (n - 128)];
    B[e * 16384 + idx] = f2b(v);
}

__global__ void k_prep_we_all(const float* __restrict__ loc_we, const float* __restrict__ glob_we,
                              ushort* __restrict__ B)  // 4 slots; loc 128x32 (K pad), glob 128x64
{
    int b = blockIdx.x;
    int e, K, Kreal, idx;
    const float* we;
    if (b < 32) { int layer = b >> 4; e = layer * 2; K = 32; Kreal = 16;
                  we = loc_we + layer * 16 * 128; idx = (b & 15) * 256 + threadIdx.x; }
    else        { int layer = (b - 32) >> 5; e = layer * 2 + 1; K = 64; Kreal = 64;
                  we = glob_we + layer * 64 * 128; idx = ((b - 32) & 31) * 256 + threadIdx.x; }
    int n = idx / K, k = idx % K;
    B[e * 8192 + idx] = (k < Kreal) ? f2b(we[k * 128 + n]) : (ushort)0;
}

// W'[h*64+i, j] = sum_k wnode[i, h*64+k] * aggw[h*64+k, j]; stored transposed (64 x 256)
__global__ void k_fold_all(const float* __restrict__ loc_wnode, const float* __restrict__ agg1_w,
                           const float* __restrict__ glob_wnode, const float* __restrict__ agg2_w,
                           ushort* __restrict__ B)  // 4 x (64 x 256)
{
    int e = blockIdx.x >> 6;
    int idx = (blockIdx.x & 63) * 256 + threadIdx.x;  // 16384
    int layer = e >> 1, gl = e & 1;
    const float* wnode = (gl ? glob_wnode : loc_wnode) + layer * 64 * 256;
    const float* aggw  = (gl ? agg2_w : agg1_w) + layer * 256 * 64;
    int j = idx >> 8, col = idx & 255;
    int h = col >> 6, ii = col & 63;
    float s = 0.f;
#pragma unroll 8
    for (int k = 0; k < 64; k++)
        s = fmaf(wnode[ii * 256 + h * 64 + k], aggw[(h * 64 + k) * 64 + j], s);
    B[e * 16384 + j * 256 + col] = f2b(s);
}

// ---------------------------------------------------------------------------
// Node kernel, zero cross-lane ops: one 16-lane group per node (all 4 heads),
// 16 groups per block, grid NN/16. Per edge: broadcast float4 score, scalar
// mask/src, one coalesced 128B hsrc row; per-lane redundant exp (cheap); each
// lane owns 4 h-columns x 4 heads, writes directly. No shuffles, no LDS.
// ---------------------------------------------------------------------------
__global__ __launch_bounds__(256) void node_fused(
    const float* __restrict__ scv,      // E x 4 fp32 (CSR order)
    const int* __restrict__ rowptr, const int* __restrict__ srcp,
    const float* __restrict__ maskp,
    const ushort* __restrict__ hsrc,    // N x 64 bf16 (layer input)
    ushort* __restrict__ zb)            // N x 256 bf16
{
    int tid = threadIdx.x;
    int n = (blockIdx.x << 4) | (tid >> 4);   // 16 groups/block, one node each
    int sl = tid & 15;
    int beg = rowptr[n], end = rowptr[n + 1];
    float l0 = 0.f, l1 = 0.f, l2 = 0.f, l3 = 0.f;
    float acc[4][4] = {};
#pragma unroll 2
    for (int i = beg; i < end; i++) {
        float4 s4 = *(const float4*)(scv + (size_t)i * 4);   // broadcast in group
        float mk = maskp[i];
        int s = srcp[i];
        uint2 hvv = *(const uint2*)(hsrc + (size_t)s * 64 + sl * 4);  // 128B/group
        float t0 = __expf(s4.x), t1 = __expf(s4.y), t2 = __expf(s4.z), t3 = __expf(s4.w);
        l0 += t0; l1 += t1; l2 += t2; l3 += t3;
        float a0 = t0 * mk, a1 = t1 * mk, a2 = t2 * mk, a3 = t3 * mk;
        float hv[4] = { b2f_lo(hvv.x), b2f_hi(hvv.x), b2f_lo(hvv.y), b2f_hi(hvv.y) };
#pragma unroll
        for (int c = 0; c < 4; c++) {
            acc[0][c] = fmaf(a0, hv[c], acc[0][c]);
            acc[1][c] = fmaf(a1, hv[c], acc[1][c]);
            acc[2][c] = fmaf(a2, hv[c], acc[2][c]);
            acc[3][c] = fmaf(a3, hv[c], acc[3][c]);
        }
    }
    float inv[4] = { 1.f / (l0 + 1e-9f), 1.f / (l1 + 1e-9f),
                     1.f / (l2 + 1e-9f), 1.f / (l3 + 1e-9f) };
#pragma unroll
    for (int h = 0; h < 4; h++) {
        uint2 o;
        o.x = (uint)f2b(acc[h][0] * inv[h]) | ((uint)f2b(acc[h][1] * inv[h]) << 16);
        o.y = (uint)f2b(acc[h][2] * inv[h]) | ((uint)f2b(acc[h][3] * inv[h]) << 16);
        *(uint2*)(zb + (size_t)n * 256 + h * 64 + sl * 4) = o;
    }
}

// ---------------------------------------------------------------------------
// Final MLP heads. One wave per batch row.
// ---------------------------------------------------------------------------
__global__ __launch_bounds__(256) void final_ui(
    const ushort* __restrict__ s0, const ushort* __restrict__ s1,
    const int* __restrict__ uidx, const int* __restrict__ iidx,
    const float* __restrict__ w1, const float* __restrict__ b1,
    const float* __restrict__ w2, const float* __restrict__ b2, float* __restrict__ out)
{
    __shared__ float xs[4][256];
    int tid = threadIdx.x, wid = tid >> 6, lane = tid & 63;
    int r = (blockIdx.x << 2) + wid;
    int u = uidx[r], it = iidx[r];
    xs[wid][lane]       = b2f(s0[(size_t)u * 64 + lane]);
    xs[wid][64 + lane]  = b2f(s1[(size_t)u * 64 + lane]);
    xs[wid][128 + lane] = b2f(s0[(size_t)it * 64 + lane]);
    xs[wid][192 + lane] = b2f(s1[(size_t)it * 64 + lane]);
    __syncthreads();
    int c = lane << 1;
    float a0 = b1[c], a1 = b1[c + 1];
    for (int k = 0; k < 256; k++) {
        float xv = xs[wid][k];
        float2 wv = *(const float2*)(w1 + (size_t)k * 128 + c);
        a0 = fmaf(xv, wv.x, a0);
        a1 = fmaf(xv, wv.y, a1);
    }
    a0 = fmaxf(a0, 0.f);
    a1 = fmaxf(a1, 0.f);
    float2 w2v = *(const float2*)(w2 + c);
    float p = a0 * w2v.x + a1 * w2v.y;
#pragma unroll
    for (int mm = 1; mm < 64; mm <<= 1) p += __shfl_xor(p, mm);
    if (lane == 0) out[r] = 1.f / (1.f + __expf(-(p + b2[0])));
}

__global__ __launch_bounds__(256) void final_sg(
    const ushort* __restrict__ s0, const ushort* __restrict__ s1,
    const int* __restrict__ gidx,
    const float* __restrict__ w1, const float* __restrict__ b1,
    const float* __restrict__ w2, const float* __restrict__ b2, float* __restrict__ out)
{
    __shared__ float xs[4][128];
    int tid = threadIdx.x, wid = tid >> 6, lane = tid & 63;
    int r = (blockIdx.x << 2) + wid;
    int n = gidx[r];
    xs[wid][lane]      = b2f(s0[(size_t)n * 64 + lane]);
    xs[wid][64 + lane] = b2f(s1[(size_t)n * 64 + lane]);
    __syncthreads();
    int c = lane << 1;
    float a0 = b1[c], a1 = b1[c + 1];
    for (int k = 0; k < 128; k++) {
        float xv = xs[wid][k];
        float2 wv = *(const float2*)(w1 + (size_t)k * 128 + c);
        a0 = fmaf(xv, wv.x, a0);
        a1 = fmaf(xv, wv.y, a1);
    }
    a0 = fmaxf(a0, 0.f);
    a1 = fmaxf(a1, 0.f);
    float2 w2v = *(const float2*)(w2 + c);
    float p = a0 * w2v.x + a1 * w2v.y;
#pragma unroll
    for (int mm = 1; mm < 64; mm <<= 1) p += __shfl_xor(p, mm);
    if (lane == 0) out[r] = 1.f / (1.f + __expf(-(p + b2[0])));
}

// ---------------------------------------------------------------------------
extern "C" void kernel_launch(void* const* d_in, const int* in_sizes, int n_in,
                              void* d_out, int out_size, void* d_ws, size_t ws_size,
                              hipStream_t stream)
{
    const float* x       = (const float*)d_in[0];
    const float* efeat   = (const float*)d_in[1];
    const float* efeat2  = (const float*)d_in[2];
    const float* mask1   = (const float*)d_in[3];
    const float* mask2   = (const float*)d_in[4];
    const int*   src     = (const int*)d_in[5];
    const int*   dst     = (const int*)d_in[6];
    const int*   uidx    = (const int*)d_in[7];
    const int*   iidx    = (const int*)d_in[8];
    const int*   gidx    = (const int*)d_in[9];
    const float* loc_wni = (const float*)d_in[10];
    const float* loc_wnj = (const float*)d_in[11];
    const float* loc_we  = (const float*)d_in[12];
    const float* loc_attn= (const float*)d_in[13];
    const float* loc_wnode=(const float*)d_in[14];
    const float* agg1_w  = (const float*)d_in[15];
    const float* agg1_b  = (const float*)d_in[16];
    const float* glob_wni= (const float*)d_in[17];
    const float* glob_wnj= (const float*)d_in[18];
    const float* glob_we = (const float*)d_in[19];
    const float* glob_attn=(const float*)d_in[20];
    const float* glob_wnode=(const float*)d_in[21];
    const float* agg2_w  = (const float*)d_in[22];
    const float* agg2_b  = (const float*)d_in[23];
    const float* w1_ui   = (const float*)d_in[24];
    const float* b1_ui   = (const float*)d_in[25];
    const float* w1_sg   = (const float*)d_in[26];
    const float* b1_sg   = (const float*)d_in[27];
    const float* w2_ui   = (const float*)d_in[28];
    const float* b2_ui   = (const float*)d_in[29];
    const float* w2_sg   = (const float*)d_in[30];
    const float* b2_sg   = (const float*)d_in[31];

    // workspace carve (all offsets 256B-aligned)
    char* wsp = (char*)d_ws;
    auto carve = [&](size_t bytes) { char* p = wsp; wsp += (bytes + 255) & ~(size_t)255; return p; };
    ushort* xfull = (ushort*)carve((size_t)NN * 256 * 2);   // lane-permuted [xi|xj]
    ushort* zb    = (ushort*)carve((size_t)NN * 256 * 2);
    ushort* hb[5];
    for (int i = 0; i < 5; i++) hb[i] = (ushort*)carve((size_t)NN * 64 * 2);
    float*  scv   = (float*)carve((size_t)NE * 16);
    float*  m1p   = (float*)carve((size_t)NE * 4);
    float*  m2p   = (float*)carve((size_t)NE * 4);
    int*    srcp  = (int*)carve((size_t)NE * 4);
    int*    dstp  = (int*)carve((size_t)NE * 4);
    int*    eidx  = (int*)carve((size_t)NE * 4);
    ushort* Bninj = (ushort*)carve(4 * 16384 * 2);
    ushort* Bwe   = (ushort*)carve(4 * 8192 * 2);
    ushort* Bfold = (ushort*)carve(4 * 16384 * 2);
    int* deg      = (int*)carve(NN * 4);
    int* rowptr   = (int*)carve((NN + 4) * 4);
    int* partials = (int*)carve(256 * 4);

    // ---- weight prep (state-independent) + CSR build + fused scatter ----
    k_prep_ninj_all<<<256, 256, 0, stream>>>(loc_wni, loc_wnj, glob_wni, glob_wnj, Bninj);
    k_prep_we_all<<<96, 256, 0, stream>>>(loc_we, glob_we, Bwe);
    k_fold_all<<<256, 256, 0, stream>>>(loc_wnode, agg1_w, glob_wnode, agg2_w, Bfold);
    hipMemsetAsync(deg, 0, NN * sizeof(int), stream);
    k_count<<<1280, 256, 0, stream>>>(dst, deg, NE);
    scan_local<<<196, 256, 0, stream>>>(deg, rowptr, partials, NN);
    scan_partials<<<1, 256, 0, stream>>>(partials, 196);
    scan_add<<<196, 256, 0, stream>>>(rowptr, partials, NN, NE);
    hipMemsetAsync(deg, 0, NN * sizeof(int), stream);
    k_scatter_perm<<<1280, 256, 0, stream>>>(dst, rowptr, deg, src, mask1, mask2,
                                             srcp, dstp, eidx, m1p, m2p, NE);
    k_cvt<<<3200, 256, 0, stream>>>(x, hb[0], NN * 64);

    auto egat = [&](const ushort* hin, int e, const float* maskp, const float* attn,
                    const float* aggb, int act, ushort* hout) {
        int is_glob = e & 1;
        // xfull = [h@wni | h@wnj], lane-permuted layout (EPI 2)
        gemm_bf16<16, 2, 0><<<782, 256, 0, stream>>>(hin, 64, NN, 64, 64,
                                                     Bninj + e * 16384, xfull,
                                                     nullptr, 0, nullptr, nullptr,
                                                     nullptr, nullptr, nullptr, nullptr);
        // scores fused into e@we GEMM epilogue (EPI 3), rows in CSR order
        if (is_glob)
            gemm_bf16<8, 3, 1><<<5000, 256, 0, stream>>>(efeat2, 64, NE, 64, 64,
                                                         Bwe + e * 8192, nullptr,
                                                         nullptr, 0, eidx, srcp, dstp,
                                                         xfull, attn, scv);
        else
            gemm_bf16<8, 3, 1><<<5000, 256, 0, stream>>>(efeat, 16, NE, 32, 16,
                                                         Bwe + e * 8192, nullptr,
                                                         nullptr, 0, eidx, srcp, dstp,
                                                         xfull, attn, scv);
        node_fused<<<NN / 16, 256, 0, stream>>>(scv, rowptr, srcp, maskp, hin, zb);
        gemm_bf16<4, 1, 0><<<782, 256, 0, stream>>>(zb, 256, NN, 256, 256,
                                                    Bfold + e * 16384, hout,
                                                    aggb, act, nullptr, nullptr,
                                                    nullptr, nullptr, nullptr, nullptr);
    };

    egat(hb[0], 0, m1p, loc_attn,        agg1_b,      0, hb[1]);
    egat(hb[1], 1, m2p, glob_attn,       agg2_b,      1, hb[2]);
    egat(hb[2], 2, m1p, loc_attn + 128,  agg1_b + 64, 0, hb[3]);
    egat(hb[3], 3, m2p, glob_attn + 128, agg2_b + 64, 1, hb[4]);

    float* out = (float*)d_out;
    final_sg<<<BATCH / 4, 256, 0, stream>>>(hb[2], hb[4], gidx, w1_sg, b1_sg, w2_sg, b2_sg, out);
    final_ui<<<BATCH / 4, 256, 0, stream>>>(hb[1], hb[3], uidx, iidx, w1_ui, b1_ui, w2_ui, b2_ui, out + BATCH);
}